// Round 10
// baseline (449.676 us; speedup 1.0000x reference)
//
#include <hip/hip_runtime.h>

typedef __attribute__((ext_vector_type(4))) float f32x4;
typedef __attribute__((ext_vector_type(8))) short s16x8;

static __device__ __forceinline__ unsigned short f2bf(float f) {
  unsigned int u = __builtin_bit_cast(unsigned int, f);
  u += 0x7fffu + ((u >> 16) & 1u);
  return (unsigned short)(u >> 16);
}
static __device__ __forceinline__ float bf2f(unsigned short u) {
  return __builtin_bit_cast(float, (unsigned int)u << 16);
}
static __device__ __forceinline__ float sigm(float x) { return 1.0f / (1.0f + __expf(-x)); }

// async global->LDS, 16B per lane. LDS dest = wave-uniform base + lane*16.
static __device__ __forceinline__ void gload16(const unsigned short* g, unsigned short* l) {
  __builtin_amdgcn_global_load_lds(
      (const __attribute__((address_space(1))) void*)g,
      (__attribute__((address_space(3))) void*)l, 16, 0, 0);
}

#define FENCE() asm volatile("" ::: "memory")
#define BAR()   { FENCE(); __builtin_amdgcn_s_barrier(); FENCE(); }
#define LGKM0() asm volatile("s_waitcnt lgkmcnt(0)" ::: "memory")

// ================= 8-phase 256^2 projection kernel (round-4 schedule, best measured) =================
// C_full[32768][2048] = A[32768][1024] @ W[2048][1024]^T, epilogue splits:
//   n<1024  -> kproj[b][m][n]; n>=1024 -> vt[b][n-1024][m] (transposed)
__global__ __launch_bounds__(512, 2) void proj_k(
    const unsigned short* __restrict__ A, const unsigned short* __restrict__ W,
    unsigned short* __restrict__ kproj, unsigned short* __restrict__ vt) {
  __shared__ unsigned short lds[2][2][2][8192];  // [buf][A/B][half][128*64]
  const int tid = threadIdx.x, lane = tid & 63, wid = tid >> 6;
  const int wm = wid >> 2, wn = wid & 3;
  // bijective XCD swizzle (nwg = 1024 = 8*128)
  const int wg = ((int)blockIdx.x & 7) * 128 + ((int)blockIdx.x >> 3);
  const int mt = wg >> 3, nt = wg & 7;
  const unsigned short* Ap = A + (long)mt * 256 * 1024;
  const unsigned short* Wp = W + (long)nt * 256 * 1024;
  const int srow = lane >> 3;                       // 0..7
  const int scol = (((lane & 7) ^ srow) << 3);      // pre-swizzled short col
  const int fr = lane & 15, fq = lane >> 4;
  const int xorv = (fr & 7) << 3;                   // read-side XOR (shorts)

#define STAGE(buf, T, h, t)                                                    \
  { const unsigned short* gp_ = (T) ? Wp : Ap;                                 \
    _Pragma("unroll") for (int p = 0; p < 2; p++) {                            \
      int r_ = wid * 16 + p * 8 + srow;                                        \
      gload16(gp_ + (long)((h) * 128 + r_) * 1024 + (long)(t) * 64 + scol,     \
              &lds[buf][T][h][(wid * 2 + p) * 512]);                           \
    } }

#define LDA_FRAG(aq)                                                           \
  { _Pragma("unroll") for (int i = 0; i < 4; i++)                              \
      _Pragma("unroll") for (int kk = 0; kk < 2; kk++)                         \
        af[i * 2 + kk] = *(const s16x8*)(Ab + ((aq) * 64 + i * 16 + fr) * 64 + \
                                         ((kk * 32 + fq * 8) ^ xorv)); }

#define LDB_FRAG(bq, arr)                                                      \
  { _Pragma("unroll") for (int j = 0; j < 2; j++)                              \
      _Pragma("unroll") for (int kk = 0; kk < 2; kk++)                         \
        arr[j * 2 + kk] = *(const s16x8*)(Bb + ((wn & 1) * 64 + ((bq) * 2 + j) * 16 + fr) * 64 + \
                                          ((kk * 32 + fq * 8) ^ xorv)); }

#define MM_Q(aq, bq, arr)                                                      \
  { __builtin_amdgcn_s_setprio(1);                                             \
    _Pragma("unroll") for (int i = 0; i < 4; i++)                              \
      _Pragma("unroll") for (int j = 0; j < 2; j++)                            \
        _Pragma("unroll") for (int kk = 0; kk < 2; kk++)                       \
          acc[(aq) * 4 + i][(bq) * 2 + j] = __builtin_amdgcn_mfma_f32_16x16x32_bf16( \
              af[i * 2 + kk], arr[j * 2 + kk], acc[(aq) * 4 + i][(bq) * 2 + j], 0, 0, 0); \
    __builtin_amdgcn_s_setprio(0); }

  f32x4 acc[8][4];
  #pragma unroll
  for (int i = 0; i < 8; i++)
    #pragma unroll
    for (int j = 0; j < 4; j++) acc[i][j] = (f32x4){0.f, 0.f, 0.f, 0.f};

  // prologue: tile0 A0,A1,B0,B1 + tile1 B0,B1
  STAGE(0, 0, 0, 0); STAGE(0, 0, 1, 0); STAGE(0, 1, 0, 0); STAGE(0, 1, 1, 0);
  STAGE(1, 1, 0, 1); STAGE(1, 1, 1, 1);
  asm volatile("s_waitcnt vmcnt(4)" ::: "memory");
  BAR();

  s16x8 af[8], b0f[4], b1f[4];
  for (int t = 0; t < 16; ++t) {
    const int pt = t & 1;
    const unsigned short* Ab = &lds[pt][0][wm][0];
    const unsigned short* Bb = &lds[pt][1][wn >> 1][0];
    // ---- phase 1: quadrant (0,0); stage A0(t+1) ----
    LDA_FRAG(0); LDB_FRAG(0, b0f);
    if (t < 15) STAGE(pt ^ 1, 0, 0, t + 1);
    BAR(); LGKM0();
    MM_Q(0, 0, b0f);
    BAR();
    // ---- phase 2: quadrant (0,1); stage A1(t+1) ----
    LDB_FRAG(1, b1f);
    if (t < 15) STAGE(pt ^ 1, 0, 1, t + 1);
    BAR(); LGKM0();
    MM_Q(0, 1, b1f);
    BAR();
    // ---- phase 3: quadrant (1,0); stage B0(t+2) ----
    LDA_FRAG(1);
    if (t < 14) STAGE(pt, 1, 0, t + 2);
    BAR(); LGKM0();
    MM_Q(1, 0, b0f);
    BAR();
    // ---- phase 4: quadrant (1,1); stage B1(t+2); counted vmcnt ----
    if (t < 14) STAGE(pt, 1, 1, t + 2);
    if (t == 14) { asm volatile("s_waitcnt vmcnt(0)" ::: "memory"); }
    else         { asm volatile("s_waitcnt vmcnt(4)" ::: "memory"); }
    BAR();
    MM_Q(1, 1, b1f);
    BAR();
  }

  // ---- epilogue: split K/V store ----
  const int nbase = nt * 256 + wn * 64;
  const bool kside = (nbase < 1024);
  #pragma unroll
  for (int i = 0; i < 8; i++) {
    const int gm0 = mt * 256 + wm * 128 + i * 16 + fq * 4;
    const int b = gm0 >> 12, mrow = gm0 & 4095;
    #pragma unroll
    for (int j = 0; j < 4; j++) {
      const int n = nbase + j * 16 + fr;
      if (kside) {
        unsigned short* dst = kproj + ((long)b * 4096 + mrow) * 1024 + n;
        #pragma unroll
        for (int q = 0; q < 4; q++) dst[(long)q * 1024] = f2bf(acc[i][j][q]);
      } else {
        ushort4 o;
        o.x = f2bf(acc[i][j][0]); o.y = f2bf(acc[i][j][1]);
        o.z = f2bf(acc[i][j][2]); o.w = f2bf(acc[i][j][3]);
        *(ushort4*)(vt + ((long)b * 1024 + (n - 1024)) * 4096 + mrow) = o;
      }
    }
  }
#undef STAGE
#undef LDA_FRAG
#undef LDB_FRAG
#undef MM_Q
}

// ---------------- rmsnorm rows of length 1024: fp32 -> bf16 (+optional raw bf16) ----------------
__global__ __launch_bounds__(256) void rmsnorm_k(const float* __restrict__ x,
                                                 const float* __restrict__ w,
                                                 unsigned short* __restrict__ y,
                                                 unsigned short* __restrict__ y_raw) {
  const int row = blockIdx.x;
  const int tid = threadIdx.x;
  const float4* xp = (const float4*)(x + (long)row * 1024);
  float4 v = xp[tid];
  float ss = v.x * v.x + v.y * v.y + v.z * v.z + v.w * v.w;
  #pragma unroll
  for (int off = 32; off; off >>= 1) ss += __shfl_xor(ss, off, 64);
  __shared__ float sb[4];
  if ((tid & 63) == 0) sb[tid >> 6] = ss;
  __syncthreads();
  float tot = sb[0] + sb[1] + sb[2] + sb[3];
  float rs = rsqrtf(tot * (1.0f / 1024.0f) + 1e-6f);
  const float4* wp = (const float4*)w;
  float4 wv = wp[tid];
  ushort4 o;
  o.x = f2bf(v.x * rs * wv.x);
  o.y = f2bf(v.y * rs * wv.y);
  o.z = f2bf(v.z * rs * wv.z);
  o.w = f2bf(v.w * rs * wv.w);
  ((ushort4*)y)[(long)row * 256 + tid] = o;
  if (y_raw) {
    ushort4 r;
    r.x = f2bf(v.x); r.y = f2bf(v.y); r.z = f2bf(v.z); r.w = f2bf(v.w);
    ((ushort4*)y_raw)[(long)row * 256 + tid] = r;
  }
}

// ---------------- fused fp32->bf16 converts ----------------
static __device__ __forceinline__ void cvt_chunk(const float* __restrict__ in,
                                                 unsigned short* __restrict__ out, long i) {
  const float4* p = (const float4*)in;
  float4 a = p[i * 2], b = p[i * 2 + 1];
  ushort4 lo, hi;
  lo.x = f2bf(a.x); lo.y = f2bf(a.y); lo.z = f2bf(a.z); lo.w = f2bf(a.w);
  hi.x = f2bf(b.x); hi.y = f2bf(b.y); hi.z = f2bf(b.z); hi.w = f2bf(b.w);
  ushort4* o = (ushort4*)out;
  o[i * 2] = lo;
  o[i * 2 + 1] = hi;
}
// grid 1024: [0,512) -> a (1M elems), [512,1024) -> b (1M elems)
__global__ __launch_bounds__(256) void cvt2_k(const float* __restrict__ a, const float* __restrict__ b,
                                              unsigned short* __restrict__ oa,
                                              unsigned short* __restrict__ ob) {
  int x = blockIdx.x;
  if (x < 512) cvt_chunk(a, oa, (long)x * 256 + threadIdx.x);
  else         cvt_chunk(b, ob, (long)(x - 512) * 256 + threadIdx.x);
}
// grid 3584: [0,512) Wq(1M), [512,2048) wi(3M), [2048,3584) wh(3M)
__global__ __launch_bounds__(256) void cvt3_k(const float* __restrict__ a, const float* __restrict__ b,
                                              const float* __restrict__ c,
                                              unsigned short* __restrict__ oa,
                                              unsigned short* __restrict__ ob,
                                              unsigned short* __restrict__ oc) {
  int x = blockIdx.x;
  if (x < 512)       cvt_chunk(a, oa, (long)x * 256 + threadIdx.x);
  else if (x < 2048) cvt_chunk(b, ob, (long)(x - 512) * 256 + threadIdx.x);
  else               cvt_chunk(c, oc, (long)(x - 2048) * 256 + threadIdx.x);
}

// ---------------- GEMM: C = alpha * A[M][K] @ W[N][K]^T (+bias) ----------------
// EPI: 0 = plain store; 2 = softmax over M(=64) -> bf16 attn + row partials.
// SPLIT: K-split batching. QGH: z=0 -> A/W cols[0,1024); z>0 -> A2/W2 slab.
// REDA: A = Cpart bf16 [batch*4+s][64][1024]; stage = sum 4 splits -> bf16 -> LDS;
//       epilogue scales row by rowinv from rs_part (batch = blockIdx.y), then +bias.
template <int BM, int BN, int WR, int WC, typename CT, int EPI, int SPLIT, int QGH, int REDA>
__global__ __launch_bounds__(WR * WC * 64) void gemm_bt(
    const unsigned short* __restrict__ A, const unsigned short* __restrict__ W,
    CT* __restrict__ C, int N, int Klen, int lda, int ldw,
    long sA, long sW, long sC, const float* __restrict__ bias,
    const float* __restrict__ bias2, float alpha, float* __restrict__ rs_part,
    const unsigned short* __restrict__ A2, const unsigned short* __restrict__ W2) {
  constexpr int BK = 64;
  constexpr int NT = WR * WC * 64;
  static_assert(NT == 256, "256 threads");
  constexpr int WSM = BM / WR, WSN = BN / WC;
  constexpr int MR = WSM / 16, NR = WSN / 16;
  constexpr int SEG_A = BM / 8, SEG_W = BN / 8;
  constexpr int PA = SEG_A / 4, PW = SEG_W / 4;
  static_assert(SEG_A % 4 == 0 && SEG_W % 4 == 0, "seg divisibility");
  __shared__ unsigned short As[BM * BK];
  __shared__ unsigned short Ws[BN * BK];
  __shared__ float rowinv_s[REDA ? 64 : 1];
  const int tid = threadIdx.x, lane = tid & 63, wid = tid >> 6;
  const int wr = wid / WC, wc = wid % WC;
  const int tileN = blockIdx.x * BN, tileM = blockIdx.y * BM;
  int coff = 0;
  int zb = 0;
  if constexpr (QGH) {
    const int zz = blockIdx.z;
    if (zz > 0) {
      A = A2;
      W = W2 + (long)(zz - 1) * 1024 * ldw;
      bias = bias2 + (zz - 1) * 1024;
      coff = zz * 1024;
    }
  } else if constexpr (!REDA) {
    zb = blockIdx.z / SPLIT;
    const int zs = blockIdx.z % SPLIT;
    A += (long)zb * sA + (long)zs * Klen;
    W += (long)zb * sW + (long)zs * Klen;
    C += (long)blockIdx.z * sC;
  }

  if constexpr (REDA) {
    // rowinv for this block's 64 rows (batch = blockIdx.y): 4 threads/row x 32 partials
    float s = 0.f;
    const float* rp = rs_part + ((long)blockIdx.y * 64 + (tid >> 2)) * 128 + (tid & 3) * 32;
    #pragma unroll
    for (int i = 0; i < 32; i++) s += rp[i];
    s += __shfl_xor(s, 1, 64);
    s += __shfl_xor(s, 2, 64);
    if ((tid & 3) == 0) rowinv_s[tid >> 2] = 1.f / (s + 1e-6f);
    // first __syncthreads in the K-loop makes this visible before epilogue
  }

  const int srow = lane >> 3;
  const int scol = (lane & 7) * 8;
  f32x4 acc[MR][NR];
  #pragma unroll
  for (int i = 0; i < MR; i++)
    #pragma unroll
    for (int j = 0; j < NR; j++) acc[i][j] = (f32x4){0.f, 0.f, 0.f, 0.f};
  const int fr = lane & 15, fq = lane >> 4;

  for (int k0 = 0; k0 < Klen; k0 += BK) {
    if constexpr (REDA) {
      // A-tile: sum 4 bf16 Cpart slabs -> bf16 -> LDS (512 chunks of 8 shorts)
      const unsigned short* Ab = A + (long)blockIdx.y * 4 * 65536 + k0;
      #pragma unroll
      for (int cc = 0; cc < 2; cc++) {
        int c = tid + cc * 256;
        int r = c >> 3, c8 = (c & 7) * 8;
        const unsigned short* src = Ab + (long)r * 1024 + c8;
        float sum[8];
        #pragma unroll
        for (int e = 0; e < 8; e++) sum[e] = 0.f;
        #pragma unroll
        for (int s = 0; s < 4; s++) {
          s16x8 v = *(const s16x8*)(src + (long)s * 65536);
          #pragma unroll
          for (int e = 0; e < 8; e++) sum[e] += bf2f((unsigned short)v[e]);
        }
        s16x8 o;
        #pragma unroll
        for (int e = 0; e < 8; e++) o[e] = (short)f2bf(sum[e]);
        *(s16x8*)(&As[r * 64 + c8]) = o;
      }
    } else {
      #pragma unroll
      for (int p = 0; p < PA; p++) {
        int seg = wid * PA + p;
        gload16(A + (long)(tileM + seg * 8 + srow) * lda + k0 + scol, &As[seg * 512]);
      }
    }
    #pragma unroll
    for (int p = 0; p < PW; p++) {
      int seg = wid * PW + p;
      gload16(W + (long)(tileN + seg * 8 + srow) * ldw + k0 + scol, &Ws[seg * 512]);
    }
    __syncthreads();
    #pragma unroll
    for (int kk = 0; kk < BK; kk += 32) {
      s16x8 af[MR], bf[NR];
      #pragma unroll
      for (int i = 0; i < MR; i++)
        af[i] = *(const s16x8*)(&As[(wr * WSM + i * 16 + fr) * BK + kk + fq * 8]);
      #pragma unroll
      for (int j = 0; j < NR; j++)
        bf[j] = *(const s16x8*)(&Ws[(wc * WSN + j * 16 + fr) * BK + kk + fq * 8]);
      #pragma unroll
      for (int i = 0; i < MR; i++)
        #pragma unroll
        for (int j = 0; j < NR; j++)
          acc[i][j] = __builtin_amdgcn_mfma_f32_16x16x32_bf16(af[i], bf[j], acc[i][j], 0, 0, 0);
    }
    __syncthreads();
  }

  if constexpr (EPI == 2) {
    static_assert(WR == 1 && BM == 64, "softmax epilogue needs full-M wave");
    #pragma unroll
    for (int i = 0; i < MR; i++)
      #pragma unroll
      for (int j = 0; j < NR; j++)
        #pragma unroll
        for (int q = 0; q < 4; q++) acc[i][j][q] *= alpha;
    float inv[NR];
    #pragma unroll
    for (int j = 0; j < NR; j++) {
      float mx = -1e30f;
      #pragma unroll
      for (int i = 0; i < MR; i++)
        #pragma unroll
        for (int q = 0; q < 4; q++) mx = fmaxf(mx, acc[i][j][q]);
      mx = fmaxf(mx, __shfl_xor(mx, 16, 64));
      mx = fmaxf(mx, __shfl_xor(mx, 32, 64));
      float sm = 0.f;
      #pragma unroll
      for (int i = 0; i < MR; i++)
        #pragma unroll
        for (int q = 0; q < 4; q++) {
          float e = __expf(acc[i][j][q] - mx);
          acc[i][j][q] = e;
          sm += e;
        }
      sm += __shfl_xor(sm, 16, 64);
      sm += __shfl_xor(sm, 32, 64);
      inv[j] = 1.f / sm;
    }
    float rp[MR][4];
    #pragma unroll
    for (int i = 0; i < MR; i++)
      #pragma unroll
      for (int q = 0; q < 4; q++) rp[i][q] = 0.f;
    unsigned short* Cs = (unsigned short*)C;
    #pragma unroll
    for (int i = 0; i < MR; i++)
      #pragma unroll
      for (int j = 0; j < NR; j++)
        #pragma unroll
        for (int q = 0; q < 4; q++) {
          float a = acc[i][j][q] * inv[j];
          rp[i][q] += a;
          Cs[(long)(i * 16 + fq * 4 + q) * N + tileN + wc * WSN + j * 16 + fr] = f2bf(a);
        }
    #pragma unroll
    for (int off = 1; off <= 8; off <<= 1)
      #pragma unroll
      for (int i = 0; i < MR; i++)
        #pragma unroll
        for (int q = 0; q < 4; q++) rp[i][q] += __shfl_xor(rp[i][q], off, 64);
    if (fr == 0) {
      const int rld = gridDim.x * WC;
      #pragma unroll
      for (int i = 0; i < MR; i++)
        #pragma unroll
        for (int q = 0; q < 4; q++)
          rs_part[((long)zb * 64 + i * 16 + fq * 4 + q) * rld + blockIdx.x * WC + wc] = rp[i][q];
    }
    return;
  }

  #pragma unroll
  for (int i = 0; i < MR; i++) {
    const int mloc = wr * WSM + i * 16 + fq * 4;
    const int mbase = tileM + mloc;
    #pragma unroll
    for (int j = 0; j < NR; j++) {
      const int n = tileN + wc * WSN + j * 16 + fr;
      const float bv = bias ? bias[n] : 0.f;
      #pragma unroll
      for (int q = 0; q < 4; q++) {
        const float sc = REDA ? rowinv_s[mloc + q] : alpha;
        float v = acc[i][j][q] * sc + bv;
        if constexpr (sizeof(CT) == 2)
          C[(long)(mbase + q) * N + coff + n] = f2bf(v);
        else
          C[(long)(mbase + q) * N + coff + n] = v;
      }
    }
  }
}

// ---- GRU combine (bf16 gi / gh-in-qgh) + fused rmsnorm of the new slots ----
__global__ __launch_bounds__(256) void gru_k(const unsigned short* __restrict__ gi,
                                             const unsigned short* __restrict__ qgh,
                                             const float* __restrict__ h,
                                             const float* __restrict__ snw,
                                             float* __restrict__ out,
                                             unsigned short* __restrict__ out_bf,
                                             unsigned short* __restrict__ sn_out) {
  const int r = blockIdx.x;
  const int tid = threadIdx.x;
  const int c = tid * 4;
  const unsigned short* gip = gi + (long)r * 3072;
  const unsigned short* ghp = qgh + (long)r * 4096 + 1024;
  ushort4 iru = *(const ushort4*)(gip + c);
  ushort4 izu = *(const ushort4*)(gip + 1024 + c);
  ushort4 inu = *(const ushort4*)(gip + 2048 + c);
  ushort4 hru = *(const ushort4*)(ghp + c);
  ushort4 hzu = *(const ushort4*)(ghp + 1024 + c);
  ushort4 hnu = *(const ushort4*)(ghp + 2048 + c);
  float4 hv = *(const float4*)(h + (long)r * 1024 + c);
  float4 o;
  { float rr = sigm(bf2f(iru.x) + bf2f(hru.x)), zz = sigm(bf2f(izu.x) + bf2f(hzu.x));
    float nn = tanhf(bf2f(inu.x) + rr * bf2f(hnu.x)); o.x = (1.f - zz) * nn + zz * hv.x; }
  { float rr = sigm(bf2f(iru.y) + bf2f(hru.y)), zz = sigm(bf2f(izu.y) + bf2f(hzu.y));
    float nn = tanhf(bf2f(inu.y) + rr * bf2f(hnu.y)); o.y = (1.f - zz) * nn + zz * hv.y; }
  { float rr = sigm(bf2f(iru.z) + bf2f(hru.z)), zz = sigm(bf2f(izu.z) + bf2f(hzu.z));
    float nn = tanhf(bf2f(inu.z) + rr * bf2f(hnu.z)); o.z = (1.f - zz) * nn + zz * hv.z; }
  { float rr = sigm(bf2f(iru.w) + bf2f(hru.w)), zz = sigm(bf2f(izu.w) + bf2f(hzu.w));
    float nn = tanhf(bf2f(inu.w) + rr * bf2f(hnu.w)); o.w = (1.f - zz) * nn + zz * hv.w; }
  *(float4*)(out + (long)r * 1024 + c) = o;
  ushort4 ob;
  ob.x = f2bf(o.x); ob.y = f2bf(o.y); ob.z = f2bf(o.z); ob.w = f2bf(o.w);
  *(ushort4*)(out_bf + (long)r * 1024 + c) = ob;
  float ss = o.x * o.x + o.y * o.y + o.z * o.z + o.w * o.w;
  #pragma unroll
  for (int off = 32; off; off >>= 1) ss += __shfl_xor(ss, off, 64);
  __shared__ float sb[4];
  if ((tid & 63) == 0) sb[tid >> 6] = ss;
  __syncthreads();
  const float tot = sb[0] + sb[1] + sb[2] + sb[3];
  const float rs = rsqrtf(tot * (1.0f / 1024.0f) + 1e-6f);
  float4 wv = *(const float4*)(snw + c);
  ushort4 so;
  so.x = f2bf(o.x * rs * wv.x); so.y = f2bf(o.y * rs * wv.y);
  so.z = f2bf(o.z * rs * wv.z); so.w = f2bf(o.w * rs * wv.w);
  *(ushort4*)(sn_out + (long)r * 1024 + c) = so;
}

extern "C" void kernel_launch(void* const* d_in, const int* in_sizes, int n_in,
                              void* d_out, int out_size, void* d_ws, size_t ws_size,
                              hipStream_t stream) {
  const float* slots_in = (const float*)d_in[0];
  const float* P        = (const float*)d_in[1];
  const float* Wq       = (const float*)d_in[2];
  const float* Wk       = (const float*)d_in[3];
  const float* Wv       = (const float*)d_in[4];
  const float* wi       = (const float*)d_in[5];
  const float* wh       = (const float*)d_in[6];
  const float* bi       = (const float*)d_in[7];
  const float* bh       = (const float*)d_in[8];
  const float* snw      = (const float*)d_in[9];
  const float* inw      = (const float*)d_in[10];

  const size_t MB = 1024ull * 1024ull;
  char* ws = (char*)d_ws;
  unsigned short* kproj = (unsigned short*)(ws + 0);        // 64MB [b][m][e] bf16
  unsigned short* vt    = (unsigned short*)(ws + 64 * MB);  // 64MB [b][e][m] bf16
  char* S               = ws + 128 * MB;                    // 64MB reuse region
  unsigned short* Pn    = (unsigned short*)(S);             // prologue only (64MB)
  unsigned short* sn    = (unsigned short*)(S);             // 1MB
  unsigned short* qgh   = (unsigned short*)(S + 1 * MB);    // 4MB [512][4096]: q | gh
  unsigned short* attnb = (unsigned short*)(S + 5 * MB);    // 4MB
  unsigned short* slotsb= (unsigned short*)(S + 9 * MB);    // 1MB
  unsigned short* gi_b  = (unsigned short*)(S + 10 * MB);   // 3MB [512][3072]
  unsigned short* Cpart = (unsigned short*)(S + 13 * MB);   // 4MB bf16 [32][64][1024]
  float* rs_part        = (float*)(S + 17 * MB);            // 256KB
  unsigned short* wq_b  = (unsigned short*)(S + 18 * MB);   // 2MB
  unsigned short* wi_b  = (unsigned short*)(S + 20 * MB);   // 6MB
  unsigned short* wh_b  = (unsigned short*)(S + 26 * MB);   // 6MB
  unsigned short* wk_b  = (unsigned short*)(ws + 192 * MB); // 2MB  } combined W [2048][1024]
  unsigned short* wv_b  = (unsigned short*)(ws + 194 * MB); // 2MB  }
  float* slots          = (float*)(ws + 196 * MB);          // 2MB

  // ---- prologue ----
  cvt2_k<<<1024, 256, 0, stream>>>(Wk, Wv, wk_b, wv_b);
  rmsnorm_k<<<32768, 256, 0, stream>>>(P, inw, Pn, nullptr);
  // combined K+V projection: M=32768, N=2048, K=1024 (8-phase 256^2)
  proj_k<<<1024, 512, 0, stream>>>(Pn, wk_b, kproj, vt);
  cvt3_k<<<3584, 256, 0, stream>>>(Wq, wi, wh, wq_b, wi_b, wh_b);
  // fused: sn = rmsnorm(slots_in), slotsb = bf16(slots_in)
  rmsnorm_k<<<512, 256, 0, stream>>>(slots_in, snw, sn, slotsb);

  // ---- 3 iterations (5 dispatches each) ----
  for (int it = 0; it < 3; ++it) {
    // merged q+gh: z=0 -> q = sn@Wq^T into qgh[:, :1024];
    //              z=1..3 -> gh slab = slotsb@wh^T+bh into qgh[:, z*1024 ..)
    gemm_bt<64, 64, 2, 2, unsigned short, 0, 1, 1, 0>
        <<<dim3(16, 8, 4), 256, 0, stream>>>(sn, wq_b, qgh, 4096, 1024, 1024, 1024,
                                             0, 0, 0, nullptr, bh, 1.f, nullptr,
                                             slotsb, wh_b);
    // attn[b][k][m] = softmax_k((q_b @ kproj_b^T)/32) + row partials
    gemm_bt<64, 128, 1, 4, unsigned short, 2, 1, 0, 0>
        <<<dim3(32, 1, 8), 256, 0, stream>>>(qgh, kproj, attnb, 4096, 1024, 4096, 1024,
                                             64L * 4096, 4096L * 1024, 64L * 4096,
                                             nullptr, nullptr, 0.03125f, rs_part,
                                             nullptr, nullptr);
    // updates partials (bf16): attn_b @ vt_b^T, K=4096 split 4x1024 (512 blocks)
    gemm_bt<64, 64, 2, 2, unsigned short, 0, 4, 0, 0>
        <<<dim3(16, 1, 32), 256, 0, stream>>>(attnb, vt, Cpart, 1024, 1024, 4096, 4096,
                                              64L * 4096, 1024L * 4096, 64L * 1024,
                                              nullptr, nullptr, 1.f, nullptr,
                                              nullptr, nullptr);
    // gi = (sum_splits Cpart * rowinv) @ wi^T + bi -> bf16 (REDA fuses the reduce)
    gemm_bt<64, 64, 2, 2, unsigned short, 0, 1, 0, 1>
        <<<dim3(48, 8, 1), 256, 0, stream>>>(Cpart, wi_b, gi_b, 3072, 1024, 1024, 1024,
                                             0, 0, 0, bi, nullptr, 1.f, rs_part,
                                             nullptr, nullptr);
    const float* hsrc = (it == 0) ? slots_in : slots;
    float* dst = (it == 2) ? (float*)d_out : slots;
    gru_k<<<512, 256, 0, stream>>>(gi_b, qgh, hsrc, snw, dst, slotsb, sn);
  }
}

// Round 12
// 387.123 us; speedup vs baseline: 1.1616x; 1.1616x over previous
//
#include <hip/hip_runtime.h>

typedef __attribute__((ext_vector_type(4))) float f32x4;
typedef __attribute__((ext_vector_type(8))) short s16x8;

static __device__ __forceinline__ unsigned short f2bf(float f) {
  unsigned int u = __builtin_bit_cast(unsigned int, f);
  u += 0x7fffu + ((u >> 16) & 1u);
  return (unsigned short)(u >> 16);
}
static __device__ __forceinline__ float bf2f(unsigned short u) {
  return __builtin_bit_cast(float, (unsigned int)u << 16);
}
static __device__ __forceinline__ float sigm(float x) { return 1.0f / (1.0f + __expf(-x)); }

// async global->LDS, 16B per lane. LDS dest = wave-uniform base + lane*16.
static __device__ __forceinline__ void gload16(const unsigned short* g, unsigned short* l) {
  __builtin_amdgcn_global_load_lds(
      (const __attribute__((address_space(1))) void*)g,
      (__attribute__((address_space(3))) void*)l, 16, 0, 0);
}

#define FENCE() asm volatile("" ::: "memory")
#define BAR()   { FENCE(); __builtin_amdgcn_s_barrier(); FENCE(); }
#define LGKM0() asm volatile("s_waitcnt lgkmcnt(0)" ::: "memory")

// ================= 8-phase 256^2 V-projection kernel (round-4 schedule) =================
// vt[b][e][m] = (A[32768][1024] @ Wv[1024][1024]^T) transposed per batch.
__global__ __launch_bounds__(512, 2) void proj_k(
    const unsigned short* __restrict__ A, const unsigned short* __restrict__ W,
    unsigned short* __restrict__ vt) {
  __shared__ unsigned short lds[2][2][2][8192];  // [buf][A/B][half][128*64]
  const int tid = threadIdx.x, lane = tid & 63, wid = tid >> 6;
  const int wm = wid >> 2, wn = wid & 3;
  // bijective XCD swizzle (nwg = 512 = 8*64)
  const int wg = ((int)blockIdx.x & 7) * 64 + ((int)blockIdx.x >> 3);
  const int mt = wg >> 2, nt = wg & 3;
  const unsigned short* Ap = A + (long)mt * 256 * 1024;
  const unsigned short* Wp = W + (long)nt * 256 * 1024;
  const int srow = lane >> 3;                       // 0..7
  const int scol = (((lane & 7) ^ srow) << 3);      // pre-swizzled short col
  const int fr = lane & 15, fq = lane >> 4;
  const int xorv = (fr & 7) << 3;                   // read-side XOR (shorts)

#define STAGE(buf, T, h, t)                                                    \
  { const unsigned short* gp_ = (T) ? Wp : Ap;                                 \
    _Pragma("unroll") for (int p = 0; p < 2; p++) {                            \
      int r_ = wid * 16 + p * 8 + srow;                                        \
      gload16(gp_ + (long)((h) * 128 + r_) * 1024 + (long)(t) * 64 + scol,     \
              &lds[buf][T][h][(wid * 2 + p) * 512]);                           \
    } }

#define LDA_FRAG(aq)                                                           \
  { _Pragma("unroll") for (int i = 0; i < 4; i++)                              \
      _Pragma("unroll") for (int kk = 0; kk < 2; kk++)                         \
        af[i * 2 + kk] = *(const s16x8*)(Ab + ((aq) * 64 + i * 16 + fr) * 64 + \
                                         ((kk * 32 + fq * 8) ^ xorv)); }

#define LDB_FRAG(bq, arr)                                                      \
  { _Pragma("unroll") for (int j = 0; j < 2; j++)                              \
      _Pragma("unroll") for (int kk = 0; kk < 2; kk++)                         \
        arr[j * 2 + kk] = *(const s16x8*)(Bb + ((wn & 1) * 64 + ((bq) * 2 + j) * 16 + fr) * 64 + \
                                          ((kk * 32 + fq * 8) ^ xorv)); }

#define MM_Q(aq, bq, arr)                                                      \
  { __builtin_amdgcn_s_setprio(1);                                             \
    _Pragma("unroll") for (int i = 0; i < 4; i++)                              \
      _Pragma("unroll") for (int j = 0; j < 2; j++)                            \
        _Pragma("unroll") for (int kk = 0; kk < 2; kk++)                       \
          acc[(aq) * 4 + i][(bq) * 2 + j] = __builtin_amdgcn_mfma_f32_16x16x32_bf16( \
              af[i * 2 + kk], arr[j * 2 + kk], acc[(aq) * 4 + i][(bq) * 2 + j], 0, 0, 0); \
    __builtin_amdgcn_s_setprio(0); }

  f32x4 acc[8][4];
  #pragma unroll
  for (int i = 0; i < 8; i++)
    #pragma unroll
    for (int j = 0; j < 4; j++) acc[i][j] = (f32x4){0.f, 0.f, 0.f, 0.f};

  // prologue: tile0 A0,A1,B0,B1 + tile1 B0,B1
  STAGE(0, 0, 0, 0); STAGE(0, 0, 1, 0); STAGE(0, 1, 0, 0); STAGE(0, 1, 1, 0);
  STAGE(1, 1, 0, 1); STAGE(1, 1, 1, 1);
  asm volatile("s_waitcnt vmcnt(4)" ::: "memory");
  BAR();

  s16x8 af[8], b0f[4], b1f[4];
  for (int t = 0; t < 16; ++t) {
    const int pt = t & 1;
    const unsigned short* Ab = &lds[pt][0][wm][0];
    const unsigned short* Bb = &lds[pt][1][wn >> 1][0];
    // ---- phase 1: quadrant (0,0); stage A0(t+1) ----
    LDA_FRAG(0); LDB_FRAG(0, b0f);
    if (t < 15) STAGE(pt ^ 1, 0, 0, t + 1);
    BAR(); LGKM0();
    MM_Q(0, 0, b0f);
    BAR();
    // ---- phase 2: quadrant (0,1); stage A1(t+1) ----
    LDB_FRAG(1, b1f);
    if (t < 15) STAGE(pt ^ 1, 0, 1, t + 1);
    BAR(); LGKM0();
    MM_Q(0, 1, b1f);
    BAR();
    // ---- phase 3: quadrant (1,0); stage B0(t+2) ----
    LDA_FRAG(1);
    if (t < 14) STAGE(pt, 1, 0, t + 2);
    BAR(); LGKM0();
    MM_Q(1, 0, b0f);
    BAR();
    // ---- phase 4: quadrant (1,1); stage B1(t+2); counted vmcnt ----
    if (t < 14) STAGE(pt, 1, 1, t + 2);
    if (t == 14) { asm volatile("s_waitcnt vmcnt(0)" ::: "memory"); }
    else         { asm volatile("s_waitcnt vmcnt(4)" ::: "memory"); }
    BAR();
    MM_Q(1, 1, b1f);
    BAR();
  }

  // ---- epilogue: transposed V store ----
  const int nbase = nt * 256 + wn * 64;
  #pragma unroll
  for (int i = 0; i < 8; i++) {
    const int gm0 = mt * 256 + wm * 128 + i * 16 + fq * 4;
    const int b = gm0 >> 12, mrow = gm0 & 4095;
    #pragma unroll
    for (int j = 0; j < 4; j++) {
      const int n = nbase + j * 16 + fr;
      ushort4 o;
      o.x = f2bf(acc[i][j][0]); o.y = f2bf(acc[i][j][1]);
      o.z = f2bf(acc[i][j][2]); o.w = f2bf(acc[i][j][3]);
      *(ushort4*)(vt + ((long)b * 1024 + n) * 4096 + mrow) = o;
    }
  }
#undef STAGE
#undef LDA_FRAG
#undef LDB_FRAG
#undef MM_Q
}

// ---------------- rmsnorm rows of length 1024: fp32 -> bf16 (+optional raw bf16) ----------------
__global__ __launch_bounds__(256) void rmsnorm_k(const float* __restrict__ x,
                                                 const float* __restrict__ w,
                                                 unsigned short* __restrict__ y,
                                                 unsigned short* __restrict__ y_raw) {
  const int row = blockIdx.x;
  const int tid = threadIdx.x;
  const float4* xp = (const float4*)(x + (long)row * 1024);
  float4 v = xp[tid];
  float ss = v.x * v.x + v.y * v.y + v.z * v.z + v.w * v.w;
  #pragma unroll
  for (int off = 32; off; off >>= 1) ss += __shfl_xor(ss, off, 64);
  __shared__ float sb[4];
  if ((tid & 63) == 0) sb[tid >> 6] = ss;
  __syncthreads();
  float tot = sb[0] + sb[1] + sb[2] + sb[3];
  float rs = rsqrtf(tot * (1.0f / 1024.0f) + 1e-6f);
  const float4* wp = (const float4*)w;
  float4 wv = wp[tid];
  ushort4 o;
  o.x = f2bf(v.x * rs * wv.x);
  o.y = f2bf(v.y * rs * wv.y);
  o.z = f2bf(v.z * rs * wv.z);
  o.w = f2bf(v.w * rs * wv.w);
  ((ushort4*)y)[(long)row * 256 + tid] = o;
  if (y_raw) {
    ushort4 r;
    r.x = f2bf(v.x); r.y = f2bf(v.y); r.z = f2bf(v.z); r.w = f2bf(v.w);
    ((ushort4*)y_raw)[(long)row * 256 + tid] = r;
  }
}

// ---------------- fp32->bf16 converts ----------------
static __device__ __forceinline__ void cvt_chunk(const float* __restrict__ in,
                                                 unsigned short* __restrict__ out, long i) {
  const float4* p = (const float4*)in;
  float4 a = p[i * 2], b = p[i * 2 + 1];
  ushort4 lo, hi;
  lo.x = f2bf(a.x); lo.y = f2bf(a.y); lo.z = f2bf(a.z); lo.w = f2bf(a.w);
  hi.x = f2bf(b.x); hi.y = f2bf(b.y); hi.z = f2bf(b.z); hi.w = f2bf(b.w);
  ushort4* o = (ushort4*)out;
  o[i * 2] = lo;
  o[i * 2 + 1] = hi;
}
__global__ __launch_bounds__(256) void cvt1_k(const float* __restrict__ a,
                                              unsigned short* __restrict__ oa) {
  cvt_chunk(a, oa, (long)blockIdx.x * 256 + threadIdx.x);
}
// grid 3072: [0,1536) wi (3M elems), [1536,3072) wh (3M elems)
__global__ __launch_bounds__(256) void cvt2b_k(const float* __restrict__ a, const float* __restrict__ b,
                                               unsigned short* __restrict__ oa,
                                               unsigned short* __restrict__ ob) {
  int x = blockIdx.x;
  if (x < 1536) cvt_chunk(a, oa, (long)x * 256 + threadIdx.x);
  else          cvt_chunk(b, ob, (long)(x - 1536) * 256 + threadIdx.x);
}

// ---------------- transpose fp32 [1024][1024] -> bf16 transposed (2 matrices) ----------------
__global__ __launch_bounds__(256) void tcvt_k(const float* __restrict__ a,
                                              const float* __restrict__ b,
                                              unsigned short* __restrict__ oa,
                                              unsigned short* __restrict__ ob) {
  __shared__ float tile[64][65];
  const float* in = (blockIdx.z == 0) ? a : b;
  unsigned short* out = (blockIdx.z == 0) ? oa : ob;
  const int r0 = blockIdx.y * 64, c0 = blockIdx.x * 64;
  const int tid = threadIdx.x;
  #pragma unroll
  for (int i = 0; i < 4; i++) {
    int idx = tid + i * 256;
    int r = idx >> 4, c4 = (idx & 15) * 4;
    float4 v = *(const float4*)(in + (long)(r0 + r) * 1024 + c0 + c4);
    tile[r][c4] = v.x; tile[r][c4 + 1] = v.y; tile[r][c4 + 2] = v.z; tile[r][c4 + 3] = v.w;
  }
  __syncthreads();
  #pragma unroll
  for (int i = 0; i < 4; i++) {
    int idx = tid + i * 256;
    int c = idx >> 4, r4 = (idx & 15) * 4;
    ushort4 o;
    o.x = f2bf(tile[r4][c]);     o.y = f2bf(tile[r4 + 1][c]);
    o.z = f2bf(tile[r4 + 2][c]); o.w = f2bf(tile[r4 + 3][c]);
    *(ushort4*)(out + (long)(c0 + c) * 1024 + r0 + r4) = o;
  }
}

// ---------------- GEMM: C = alpha * A[M][K] @ W[N][K]^T (+bias) ----------------
// EPI: 0 = plain store; 2 = softmax over M(=64) -> bf16 attn + row partials.
// SPLIT: K-split batching. QGH: z=0 -> A/W cols[0,1024); z>0 -> A2/W2 slab.
template <int BM, int BN, int WR, int WC, typename CT, int EPI, int SPLIT, int QGH>
__global__ __launch_bounds__(WR * WC * 64) void gemm_bt(
    const unsigned short* __restrict__ A, const unsigned short* __restrict__ W,
    CT* __restrict__ C, int N, int Klen, int lda, int ldw,
    long sA, long sW, long sC, const float* __restrict__ bias,
    const float* __restrict__ bias2, float alpha, float* __restrict__ rs_part,
    const unsigned short* __restrict__ A2, const unsigned short* __restrict__ W2) {
  constexpr int BK = 64;
  constexpr int NT = WR * WC * 64;
  static_assert(NT == 256, "256 threads");
  constexpr int WSM = BM / WR, WSN = BN / WC;
  constexpr int MR = WSM / 16, NR = WSN / 16;
  constexpr int SEG_A = BM / 8, SEG_W = BN / 8;
  constexpr int PA = SEG_A / 4, PW = SEG_W / 4;
  static_assert(SEG_A % 4 == 0 && SEG_W % 4 == 0, "seg divisibility");
  __shared__ unsigned short As[BM * BK];
  __shared__ unsigned short Ws[BN * BK];
  const int tid = threadIdx.x, lane = tid & 63, wid = tid >> 6;
  const int wr = wid / WC, wc = wid % WC;
  const int tileN = blockIdx.x * BN, tileM = blockIdx.y * BM;
  int coff = 0;
  int zb = 0;
  if constexpr (QGH) {
    const int zz = blockIdx.z;
    if (zz > 0) {
      A = A2;
      W = W2 + (long)(zz - 1) * 1024 * ldw;
      bias = bias2 + (zz - 1) * 1024;
      coff = zz * 1024;
    }
  } else {
    zb = blockIdx.z / SPLIT;
    const int zs = blockIdx.z % SPLIT;
    A += (long)zb * sA + (long)zs * Klen;
    W += (long)zb * sW + (long)zs * Klen;
    C += (long)blockIdx.z * sC;
  }
  const int srow = lane >> 3;
  const int scol = (lane & 7) * 8;
  f32x4 acc[MR][NR];
  #pragma unroll
  for (int i = 0; i < MR; i++)
    #pragma unroll
    for (int j = 0; j < NR; j++) acc[i][j] = (f32x4){0.f, 0.f, 0.f, 0.f};
  const int fr = lane & 15, fq = lane >> 4;

  for (int k0 = 0; k0 < Klen; k0 += BK) {
    #pragma unroll
    for (int p = 0; p < PA; p++) {
      int seg = wid * PA + p;
      gload16(A + (long)(tileM + seg * 8 + srow) * lda + k0 + scol, &As[seg * 512]);
    }
    #pragma unroll
    for (int p = 0; p < PW; p++) {
      int seg = wid * PW + p;
      gload16(W + (long)(tileN + seg * 8 + srow) * ldw + k0 + scol, &Ws[seg * 512]);
    }
    __syncthreads();
    #pragma unroll
    for (int kk = 0; kk < BK; kk += 32) {
      s16x8 af[MR], bf[NR];
      #pragma unroll
      for (int i = 0; i < MR; i++)
        af[i] = *(const s16x8*)(&As[(wr * WSM + i * 16 + fr) * BK + kk + fq * 8]);
      #pragma unroll
      for (int j = 0; j < NR; j++)
        bf[j] = *(const s16x8*)(&Ws[(wc * WSN + j * 16 + fr) * BK + kk + fq * 8]);
      #pragma unroll
      for (int i = 0; i < MR; i++)
        #pragma unroll
        for (int j = 0; j < NR; j++)
          acc[i][j] = __builtin_amdgcn_mfma_f32_16x16x32_bf16(af[i], bf[j], acc[i][j], 0, 0, 0);
    }
    __syncthreads();
  }

  if constexpr (EPI == 2) {
    static_assert(WR == 1 && BM == 64, "softmax epilogue needs full-M wave");
    #pragma unroll
    for (int i = 0; i < MR; i++)
      #pragma unroll
      for (int j = 0; j < NR; j++)
        #pragma unroll
        for (int q = 0; q < 4; q++) acc[i][j][q] *= alpha;
    float inv[NR];
    #pragma unroll
    for (int j = 0; j < NR; j++) {
      float mx = -1e30f;
      #pragma unroll
      for (int i = 0; i < MR; i++)
        #pragma unroll
        for (int q = 0; q < 4; q++) mx = fmaxf(mx, acc[i][j][q]);
      mx = fmaxf(mx, __shfl_xor(mx, 16, 64));
      mx = fmaxf(mx, __shfl_xor(mx, 32, 64));
      float sm = 0.f;
      #pragma unroll
      for (int i = 0; i < MR; i++)
        #pragma unroll
        for (int q = 0; q < 4; q++) {
          float e = __expf(acc[i][j][q] - mx);
          acc[i][j][q] = e;
          sm += e;
        }
      sm += __shfl_xor(sm, 16, 64);
      sm += __shfl_xor(sm, 32, 64);
      inv[j] = 1.f / sm;
    }
    float rp[MR][4];
    #pragma unroll
    for (int i = 0; i < MR; i++)
      #pragma unroll
      for (int q = 0; q < 4; q++) rp[i][q] = 0.f;
    unsigned short* Cs = (unsigned short*)C;
    #pragma unroll
    for (int i = 0; i < MR; i++)
      #pragma unroll
      for (int j = 0; j < NR; j++)
        #pragma unroll
        for (int q = 0; q < 4; q++) {
          float a = acc[i][j][q] * inv[j];
          rp[i][q] += a;
          Cs[(long)(i * 16 + fq * 4 + q) * N + tileN + wc * WSN + j * 16 + fr] = f2bf(a);
        }
    #pragma unroll
    for (int off = 1; off <= 8; off <<= 1)
      #pragma unroll
      for (int i = 0; i < MR; i++)
        #pragma unroll
        for (int q = 0; q < 4; q++) rp[i][q] += __shfl_xor(rp[i][q], off, 64);
    if (fr == 0) {
      const int rld = gridDim.x * WC;
      #pragma unroll
      for (int i = 0; i < MR; i++)
        #pragma unroll
        for (int q = 0; q < 4; q++)
          rs_part[((long)zb * 64 + i * 16 + fq * 4 + q) * rld + blockIdx.x * WC + wc] = rp[i][q];
    }
    return;
  }

  #pragma unroll
  for (int i = 0; i < MR; i++) {
    const int mbase = tileM + wr * WSM + i * 16 + fq * 4;
    #pragma unroll
    for (int j = 0; j < NR; j++) {
      const int n = tileN + wc * WSN + j * 16 + fr;
      const float bv = bias ? bias[n] : 0.f;
      #pragma unroll
      for (int q = 0; q < 4; q++) {
        float v = acc[i][j][q] * alpha + bv;
        if constexpr (sizeof(CT) == 2)
          C[(long)(mbase + q) * N + coff + n] = f2bf(v);
        else
          C[(long)(mbase + q) * N + coff + n] = v;
      }
    }
  }
}

// ---- reduce 8 bf16 K-splits; in-block rowsum of rs_part -> rowinv; scale; cast bf16 ----
__global__ __launch_bounds__(256) void upd_reduce_k(const unsigned short* __restrict__ part,
                                                    const float* __restrict__ rs_part,
                                                    unsigned short* __restrict__ out) {
  const int row = blockIdx.x;  // b*64 + k
  const int tid = threadIdx.x;
  float s = (tid < 128) ? rs_part[(long)row * 128 + tid] : 0.f;
  #pragma unroll
  for (int off = 32; off; off >>= 1) s += __shfl_xor(s, off, 64);
  __shared__ float sb[4];
  if ((tid & 63) == 0) sb[tid >> 6] = s;
  __syncthreads();
  const float inv = 1.f / (sb[0] + sb[1] + sb[2] + sb[3] + 1e-6f);
  const unsigned short* base =
      part + (long)(row >> 6) * 8 * 65536 + (long)(row & 63) * 1024 + tid * 4;
  float ax = 0.f, ay = 0.f, az = 0.f, aw = 0.f;
  #pragma unroll
  for (int sp = 0; sp < 8; sp++) {
    ushort4 v = *(const ushort4*)(base + (long)sp * 65536);
    ax += bf2f(v.x); ay += bf2f(v.y); az += bf2f(v.z); aw += bf2f(v.w);
  }
  ushort4 o;
  o.x = f2bf(ax * inv); o.y = f2bf(ay * inv);
  o.z = f2bf(az * inv); o.w = f2bf(aw * inv);
  ((ushort4*)out)[(long)row * 256 + tid] = o;
}

// ---- GRU combine (bf16 gi / gh-in-qgh) + fused rmsnorm of the new slots ----
__global__ __launch_bounds__(256) void gru_k(const unsigned short* __restrict__ gi,
                                             const unsigned short* __restrict__ qgh,
                                             const float* __restrict__ h,
                                             const float* __restrict__ snw,
                                             float* __restrict__ out,
                                             unsigned short* __restrict__ out_bf,
                                             unsigned short* __restrict__ sn_out) {
  const int r = blockIdx.x;
  const int tid = threadIdx.x;
  const int c = tid * 4;
  const unsigned short* gip = gi + (long)r * 3072;
  const unsigned short* ghp = qgh + (long)r * 4096 + 1024;
  ushort4 iru = *(const ushort4*)(gip + c);
  ushort4 izu = *(const ushort4*)(gip + 1024 + c);
  ushort4 inu = *(const ushort4*)(gip + 2048 + c);
  ushort4 hru = *(const ushort4*)(ghp + c);
  ushort4 hzu = *(const ushort4*)(ghp + 1024 + c);
  ushort4 hnu = *(const ushort4*)(ghp + 2048 + c);
  float4 hv = *(const float4*)(h + (long)r * 1024 + c);
  float4 o;
  { float rr = sigm(bf2f(iru.x) + bf2f(hru.x)), zz = sigm(bf2f(izu.x) + bf2f(hzu.x));
    float nn = tanhf(bf2f(inu.x) + rr * bf2f(hnu.x)); o.x = (1.f - zz) * nn + zz * hv.x; }
  { float rr = sigm(bf2f(iru.y) + bf2f(hru.y)), zz = sigm(bf2f(izu.y) + bf2f(hzu.y));
    float nn = tanhf(bf2f(inu.y) + rr * bf2f(hnu.y)); o.y = (1.f - zz) * nn + zz * hv.y; }
  { float rr = sigm(bf2f(iru.z) + bf2f(hru.z)), zz = sigm(bf2f(izu.z) + bf2f(hzu.z));
    float nn = tanhf(bf2f(inu.z) + rr * bf2f(hnu.z)); o.z = (1.f - zz) * nn + zz * hv.z; }
  { float rr = sigm(bf2f(iru.w) + bf2f(hru.w)), zz = sigm(bf2f(izu.w) + bf2f(hzu.w));
    float nn = tanhf(bf2f(inu.w) + rr * bf2f(hnu.w)); o.w = (1.f - zz) * nn + zz * hv.w; }
  *(float4*)(out + (long)r * 1024 + c) = o;
  ushort4 ob;
  ob.x = f2bf(o.x); ob.y = f2bf(o.y); ob.z = f2bf(o.z); ob.w = f2bf(o.w);
  *(ushort4*)(out_bf + (long)r * 1024 + c) = ob;
  float ss = o.x * o.x + o.y * o.y + o.z * o.z + o.w * o.w;
  #pragma unroll
  for (int off = 32; off; off >>= 1) ss += __shfl_xor(ss, off, 64);
  __shared__ float sb[4];
  if ((tid & 63) == 0) sb[tid >> 6] = ss;
  __syncthreads();
  const float tot = sb[0] + sb[1] + sb[2] + sb[3];
  const float rs = rsqrtf(tot * (1.0f / 1024.0f) + 1e-6f);
  float4 wv = *(const float4*)(snw + c);
  ushort4 so;
  so.x = f2bf(o.x * rs * wv.x); so.y = f2bf(o.y * rs * wv.y);
  so.z = f2bf(o.z * rs * wv.z); so.w = f2bf(o.w * rs * wv.w);
  *(ushort4*)(sn_out + (long)r * 1024 + c) = so;
}

extern "C" void kernel_launch(void* const* d_in, const int* in_sizes, int n_in,
                              void* d_out, int out_size, void* d_ws, size_t ws_size,
                              hipStream_t stream) {
  const float* slots_in = (const float*)d_in[0];
  const float* P        = (const float*)d_in[1];
  const float* Wq       = (const float*)d_in[2];
  const float* Wk       = (const float*)d_in[3];
  const float* Wv       = (const float*)d_in[4];
  const float* wi       = (const float*)d_in[5];
  const float* wh       = (const float*)d_in[6];
  const float* bi       = (const float*)d_in[7];
  const float* bh       = (const float*)d_in[8];
  const float* snw      = (const float*)d_in[9];
  const float* inw      = (const float*)d_in[10];

  const size_t MB = 1024ull * 1024ull;
  char* ws = (char*)d_ws;
  unsigned short* Pn    = (unsigned short*)(ws + 0);        // 64MB [b][m][e] bf16 (persists!)
  unsigned short* vt    = (unsigned short*)(ws + 64 * MB);  // 64MB [b][e][m] bf16
  char* S               = ws + 128 * MB;                    // iteration region
  unsigned short* sn    = (unsigned short*)(S);             // 1MB
  unsigned short* qgh   = (unsigned short*)(S + 1 * MB);    // 4MB [512][4096]: qm | gh
  unsigned short* attnb = (unsigned short*)(S + 5 * MB);    // 4MB
  unsigned short* updb  = (unsigned short*)(S + 9 * MB);    // 1MB
  unsigned short* slotsb= (unsigned short*)(S + 10 * MB);   // 1MB
  unsigned short* gi_b  = (unsigned short*)(S + 11 * MB);   // 3MB [512][3072]
  unsigned short* Cpart = (unsigned short*)(S + 14 * MB);   // 8MB bf16 [64][64][1024]
  float* rs_part        = (float*)(S + 22 * MB);            // 256KB
  unsigned short* wi_b  = (unsigned short*)(S + 23 * MB);   // 6MB
  unsigned short* wh_b  = (unsigned short*)(S + 29 * MB);   // 6MB
  unsigned short* wv_b  = (unsigned short*)(S + 35 * MB);   // 2MB
  unsigned short* wqt   = (unsigned short*)(S + 37 * MB);   // 2MB (Wq^T bf16)
  unsigned short* wkt   = (unsigned short*)(S + 39 * MB);   // 2MB (Wk^T bf16)
  unsigned short* m1_b  = (unsigned short*)(S + 41 * MB);   // 2MB  M1[b][a] = sum_e Wk[e,b]Wq[e,a]
  float* slots          = (float*)(ws + 196 * MB);          // 2MB

  // ---- prologue ----
  cvt1_k<<<512, 256, 0, stream>>>(Wv, wv_b);
  rmsnorm_k<<<32768, 256, 0, stream>>>(P, inw, Pn, nullptr);
  // V-only projection: M=32768, N=1024, K=1024 (8-phase 256^2, 512 blocks)
  proj_k<<<512, 512, 0, stream>>>(Pn, wv_b, vt);
  // M1 = Wk^T @ Wq (via transposed bf16 copies): C[b,a] = sum_e Wk[e,b] Wq[e,a]
  tcvt_k<<<dim3(16, 16, 2), 256, 0, stream>>>(Wq, Wk, wqt, wkt);
  gemm_bt<64, 64, 2, 2, unsigned short, 0, 1, 0>
      <<<dim3(16, 16, 1), 256, 0, stream>>>(wkt, wqt, m1_b, 1024, 1024, 1024, 1024,
                                            0, 0, 0, nullptr, nullptr, 1.f, nullptr,
                                            nullptr, nullptr);
  cvt2b_k<<<3072, 256, 0, stream>>>(wi, wh, wi_b, wh_b);
  // fused: sn = rmsnorm(slots_in), slotsb = bf16(slots_in)
  rmsnorm_k<<<512, 256, 0, stream>>>(slots_in, snw, sn, slotsb);

  // ---- 3 iterations (6 dispatches each) ----
  for (int it = 0; it < 3; ++it) {
    // merged qm+gh: z=0 -> qm = sn@M1^T into qgh[:, :1024]
    //               z=1..3 -> gh slab = slotsb@wh^T+bh into qgh[:, z*1024 ..)
    gemm_bt<64, 64, 2, 2, unsigned short, 0, 1, 1>
        <<<dim3(16, 8, 4), 256, 0, stream>>>(sn, m1_b, qgh, 4096, 1024, 1024, 1024,
                                             0, 0, 0, nullptr, bh, 1.f, nullptr,
                                             slotsb, wh_b);
    // attn[b][k][m] = softmax_k((qm_b @ Pn_b^T)/32) + row partials
    gemm_bt<64, 128, 1, 4, unsigned short, 2, 1, 0>
        <<<dim3(32, 1, 8), 256, 0, stream>>>(qgh, Pn, attnb, 4096, 1024, 4096, 1024,
                                             64L * 4096, 4096L * 1024, 64L * 4096,
                                             nullptr, nullptr, 0.03125f, rs_part,
                                             nullptr, nullptr);
    // updates partials (bf16): attn_b @ vt_b^T, K=4096 split 8x512 (1024 blocks)
    gemm_bt<64, 64, 2, 2, unsigned short, 0, 8, 0>
        <<<dim3(16, 1, 64), 256, 0, stream>>>(attnb, vt, Cpart, 1024, 512, 4096, 4096,
                                              64L * 4096, 1024L * 4096, 64L * 1024,
                                              nullptr, nullptr, 1.f, nullptr,
                                              nullptr, nullptr);
    upd_reduce_k<<<512, 256, 0, stream>>>(Cpart, rs_part, updb);
    // gi = updb @ wi^T + bi -> bf16 [512][3072]
    gemm_bt<64, 64, 2, 2, unsigned short, 0, 1, 0>
        <<<dim3(48, 8, 1), 256, 0, stream>>>(updb, wi_b, gi_b, 3072, 1024, 1024, 1024,
                                             0, 0, 0, bi, nullptr, 1.f, nullptr,
                                             nullptr, nullptr);
    const float* hsrc = (it == 0) ? slots_in : slots;
    float* dst = (it == 2) ? (float*)d_out : slots;
    gru_k<<<512, 256, 0, stream>>>(gi_b, qgh, hsrc, snw, dst, slotsb, sn);
  }
}

// Round 13
// 356.166 us; speedup vs baseline: 1.2625x; 1.0869x over previous
//
#include <hip/hip_runtime.h>

typedef __attribute__((ext_vector_type(4))) float f32x4;
typedef __attribute__((ext_vector_type(8))) short s16x8;

static __device__ __forceinline__ unsigned short f2bf(float f) {
  unsigned int u = __builtin_bit_cast(unsigned int, f);
  u += 0x7fffu + ((u >> 16) & 1u);
  return (unsigned short)(u >> 16);
}
static __device__ __forceinline__ float bf2f(unsigned short u) {
  return __builtin_bit_cast(float, (unsigned int)u << 16);
}
static __device__ __forceinline__ float sigm(float x) { return 1.0f / (1.0f + __expf(-x)); }

// async global->LDS, 16B per lane. LDS dest = wave-uniform base + lane*16.
static __device__ __forceinline__ void gload16(const unsigned short* g, unsigned short* l) {
  __builtin_amdgcn_global_load_lds(
      (const __attribute__((address_space(1))) void*)g,
      (__attribute__((address_space(3))) void*)l, 16, 0, 0);
}

// ---------------- rmsnorm rows of length 1024: fp32 -> bf16 (+optional raw bf16) ----------------
__global__ __launch_bounds__(256) void rmsnorm_k(const float* __restrict__ x,
                                                 const float* __restrict__ w,
                                                 unsigned short* __restrict__ y,
                                                 unsigned short* __restrict__ y_raw) {
  const int row = blockIdx.x;
  const int tid = threadIdx.x;
  const float4* xp = (const float4*)(x + (long)row * 1024);
  float4 v = xp[tid];
  float ss = v.x * v.x + v.y * v.y + v.z * v.z + v.w * v.w;
  #pragma unroll
  for (int off = 32; off; off >>= 1) ss += __shfl_xor(ss, off, 64);
  __shared__ float sb[4];
  if ((tid & 63) == 0) sb[tid >> 6] = ss;
  __syncthreads();
  float tot = sb[0] + sb[1] + sb[2] + sb[3];
  float rs = rsqrtf(tot * (1.0f / 1024.0f) + 1e-6f);
  const float4* wp = (const float4*)w;
  float4 wv = wp[tid];
  ushort4 o;
  o.x = f2bf(v.x * rs * wv.x);
  o.y = f2bf(v.y * rs * wv.y);
  o.z = f2bf(v.z * rs * wv.z);
  o.w = f2bf(v.w * rs * wv.w);
  ((ushort4*)y)[(long)row * 256 + tid] = o;
  if (y_raw) {
    ushort4 r;
    r.x = f2bf(v.x); r.y = f2bf(v.y); r.z = f2bf(v.z); r.w = f2bf(v.w);
    ((ushort4*)y_raw)[(long)row * 256 + tid] = r;
  }
}

// ---------------- bf16 transpose: Pn[b][4096 m][1024 d] -> Pnt[b][1024 d][4096 m] ----------------
// grid 8192: b = x>>10, mt = (x&1023)>>4, dt = x&15; 64x64 tiles.
__global__ __launch_bounds__(256) void tp_k(const unsigned short* __restrict__ in,
                                            unsigned short* __restrict__ out) {
  __shared__ unsigned short t[64][65];
  const int x = blockIdx.x;
  const int b = x >> 10;
  const int mt = (x & 1023) >> 4;
  const int dt = x & 15;
  const int tid = threadIdx.x;
  const long ibase = (long)b * 4096 * 1024 + (long)mt * 64 * 1024 + dt * 64;
  #pragma unroll
  for (int i = 0; i < 4; i++) {
    int idx = tid + i * 256;
    int r = idx >> 4, c4 = (idx & 15) * 4;
    ushort4 v = *(const ushort4*)(in + ibase + (long)r * 1024 + c4);
    t[r][c4] = v.x; t[r][c4 + 1] = v.y; t[r][c4 + 2] = v.z; t[r][c4 + 3] = v.w;
  }
  __syncthreads();
  const long obase = (long)b * 1024 * 4096 + (long)dt * 64 * 4096 + mt * 64;
  #pragma unroll
  for (int i = 0; i < 4; i++) {
    int idx = tid + i * 256;
    int r = idx >> 4, c4 = (idx & 15) * 4;
    ushort4 o;
    o.x = t[c4][r]; o.y = t[c4 + 1][r]; o.z = t[c4 + 2][r]; o.w = t[c4 + 3][r];
    *(ushort4*)(out + obase + (long)r * 4096 + c4) = o;
  }
}

// ---------------- fp32->bf16 converts ----------------
static __device__ __forceinline__ void cvt_chunk(const float* __restrict__ in,
                                                 unsigned short* __restrict__ out, long i) {
  const float4* p = (const float4*)in;
  float4 a = p[i * 2], b = p[i * 2 + 1];
  ushort4 lo, hi;
  lo.x = f2bf(a.x); lo.y = f2bf(a.y); lo.z = f2bf(a.z); lo.w = f2bf(a.w);
  hi.x = f2bf(b.x); hi.y = f2bf(b.y); hi.z = f2bf(b.z); hi.w = f2bf(b.w);
  ushort4* o = (ushort4*)out;
  o[i * 2] = lo;
  o[i * 2 + 1] = hi;
}
// grid 3072: [0,1536) wi (3M elems), [1536,3072) wh (3M elems)
__global__ __launch_bounds__(256) void cvt2b_k(const float* __restrict__ a, const float* __restrict__ b,
                                               unsigned short* __restrict__ oa,
                                               unsigned short* __restrict__ ob) {
  int x = blockIdx.x;
  if (x < 1536) cvt_chunk(a, oa, (long)x * 256 + threadIdx.x);
  else          cvt_chunk(b, ob, (long)(x - 1536) * 256 + threadIdx.x);
}

// ---------------- transpose fp32 [1024][1024] -> bf16 transposed (3 matrices) ----------------
__global__ __launch_bounds__(256) void tcvt_k(const float* __restrict__ a,
                                              const float* __restrict__ b,
                                              const float* __restrict__ c,
                                              unsigned short* __restrict__ oa,
                                              unsigned short* __restrict__ ob,
                                              unsigned short* __restrict__ oc) {
  __shared__ float tile[64][65];
  const float* in = (blockIdx.z == 0) ? a : (blockIdx.z == 1) ? b : c;
  unsigned short* out = (blockIdx.z == 0) ? oa : (blockIdx.z == 1) ? ob : oc;
  const int r0 = blockIdx.y * 64, c0 = blockIdx.x * 64;
  const int tid = threadIdx.x;
  #pragma unroll
  for (int i = 0; i < 4; i++) {
    int idx = tid + i * 256;
    int r = idx >> 4, c4 = (idx & 15) * 4;
    float4 v = *(const float4*)(in + (long)(r0 + r) * 1024 + c0 + c4);
    tile[r][c4] = v.x; tile[r][c4 + 1] = v.y; tile[r][c4 + 2] = v.z; tile[r][c4 + 3] = v.w;
  }
  __syncthreads();
  #pragma unroll
  for (int i = 0; i < 4; i++) {
    int idx = tid + i * 256;
    int c = idx >> 4, r4 = (idx & 15) * 4;
    ushort4 o;
    o.x = f2bf(tile[r4][c]);     o.y = f2bf(tile[r4 + 1][c]);
    o.z = f2bf(tile[r4 + 2][c]); o.w = f2bf(tile[r4 + 3][c]);
    *(ushort4*)(out + (long)(c0 + c) * 1024 + r0 + r4) = o;
  }
}

// ---------------- GEMM: C = alpha * A[M][K] @ W[N][K]^T (+bias) ----------------
// EPI: 0 = plain store; 2 = softmax over M(=64) -> bf16 attn + row partials.
// SPLIT: K-split batching. QGH: z=0 -> A/W cols[0,1024); z>0 -> A2/W2 slab.
template <int BM, int BN, int WR, int WC, typename CT, int EPI, int SPLIT, int QGH>
__global__ __launch_bounds__(WR * WC * 64) void gemm_bt(
    const unsigned short* __restrict__ A, const unsigned short* __restrict__ W,
    CT* __restrict__ C, int N, int Klen, int lda, int ldw,
    long sA, long sW, long sC, const float* __restrict__ bias,
    const float* __restrict__ bias2, float alpha, float* __restrict__ rs_part,
    const unsigned short* __restrict__ A2, const unsigned short* __restrict__ W2) {
  constexpr int BK = 64;
  constexpr int NT = WR * WC * 64;
  static_assert(NT == 256, "256 threads");
  constexpr int WSM = BM / WR, WSN = BN / WC;
  constexpr int MR = WSM / 16, NR = WSN / 16;
  constexpr int SEG_A = BM / 8, SEG_W = BN / 8;
  constexpr int PA = SEG_A / 4, PW = SEG_W / 4;
  static_assert(SEG_A % 4 == 0 && SEG_W % 4 == 0, "seg divisibility");
  __shared__ unsigned short As[BM * BK];
  __shared__ unsigned short Ws[BN * BK];
  const int tid = threadIdx.x, lane = tid & 63, wid = tid >> 6;
  const int wr = wid / WC, wc = wid % WC;
  const int tileN = blockIdx.x * BN, tileM = blockIdx.y * BM;
  int coff = 0;
  int zb = 0;
  if constexpr (QGH) {
    const int zz = blockIdx.z;
    if (zz > 0) {
      A = A2;
      W = W2 + (long)(zz - 1) * 1024 * ldw;
      bias = bias2 + (zz - 1) * 1024;
      coff = zz * 1024;
    }
  } else {
    zb = blockIdx.z / SPLIT;
    const int zs = blockIdx.z % SPLIT;
    A += (long)zb * sA + (long)zs * Klen;
    W += (long)zb * sW + (long)zs * Klen;
    C += (long)blockIdx.z * sC;
  }
  const int srow = lane >> 3;
  const int scol = (lane & 7) * 8;
  f32x4 acc[MR][NR];
  #pragma unroll
  for (int i = 0; i < MR; i++)
    #pragma unroll
    for (int j = 0; j < NR; j++) acc[i][j] = (f32x4){0.f, 0.f, 0.f, 0.f};
  const int fr = lane & 15, fq = lane >> 4;

  for (int k0 = 0; k0 < Klen; k0 += BK) {
    #pragma unroll
    for (int p = 0; p < PA; p++) {
      int seg = wid * PA + p;
      gload16(A + (long)(tileM + seg * 8 + srow) * lda + k0 + scol, &As[seg * 512]);
    }
    #pragma unroll
    for (int p = 0; p < PW; p++) {
      int seg = wid * PW + p;
      gload16(W + (long)(tileN + seg * 8 + srow) * ldw + k0 + scol, &Ws[seg * 512]);
    }
    __syncthreads();
    #pragma unroll
    for (int kk = 0; kk < BK; kk += 32) {
      s16x8 af[MR], bf[NR];
      #pragma unroll
      for (int i = 0; i < MR; i++)
        af[i] = *(const s16x8*)(&As[(wr * WSM + i * 16 + fr) * BK + kk + fq * 8]);
      #pragma unroll
      for (int j = 0; j < NR; j++)
        bf[j] = *(const s16x8*)(&Ws[(wc * WSN + j * 16 + fr) * BK + kk + fq * 8]);
      #pragma unroll
      for (int i = 0; i < MR; i++)
        #pragma unroll
        for (int j = 0; j < NR; j++)
          acc[i][j] = __builtin_amdgcn_mfma_f32_16x16x32_bf16(af[i], bf[j], acc[i][j], 0, 0, 0);
    }
    __syncthreads();
  }

  if constexpr (EPI == 2) {
    static_assert(WR == 1 && BM == 64, "softmax epilogue needs full-M wave");
    #pragma unroll
    for (int i = 0; i < MR; i++)
      #pragma unroll
      for (int j = 0; j < NR; j++)
        #pragma unroll
        for (int q = 0; q < 4; q++) acc[i][j][q] *= alpha;
    float inv[NR];
    #pragma unroll
    for (int j = 0; j < NR; j++) {
      float mx = -1e30f;
      #pragma unroll
      for (int i = 0; i < MR; i++)
        #pragma unroll
        for (int q = 0; q < 4; q++) mx = fmaxf(mx, acc[i][j][q]);
      mx = fmaxf(mx, __shfl_xor(mx, 16, 64));
      mx = fmaxf(mx, __shfl_xor(mx, 32, 64));
      float sm = 0.f;
      #pragma unroll
      for (int i = 0; i < MR; i++)
        #pragma unroll
        for (int q = 0; q < 4; q++) {
          float e = __expf(acc[i][j][q] - mx);
          acc[i][j][q] = e;
          sm += e;
        }
      sm += __shfl_xor(sm, 16, 64);
      sm += __shfl_xor(sm, 32, 64);
      inv[j] = 1.f / sm;
    }
    float rp[MR][4];
    #pragma unroll
    for (int i = 0; i < MR; i++)
      #pragma unroll
      for (int q = 0; q < 4; q++) rp[i][q] = 0.f;
    unsigned short* Cs = (unsigned short*)C;
    #pragma unroll
    for (int i = 0; i < MR; i++)
      #pragma unroll
      for (int j = 0; j < NR; j++)
        #pragma unroll
        for (int q = 0; q < 4; q++) {
          float a = acc[i][j][q] * inv[j];
          rp[i][q] += a;
          Cs[(long)(i * 16 + fq * 4 + q) * N + tileN + wc * WSN + j * 16 + fr] = f2bf(a);
        }
    #pragma unroll
    for (int off = 1; off <= 8; off <<= 1)
      #pragma unroll
      for (int i = 0; i < MR; i++)
        #pragma unroll
        for (int q = 0; q < 4; q++) rp[i][q] += __shfl_xor(rp[i][q], off, 64);
    if (fr == 0) {
      const int rld = gridDim.x * WC;
      #pragma unroll
      for (int i = 0; i < MR; i++)
        #pragma unroll
        for (int q = 0; q < 4; q++)
          rs_part[((long)zb * 64 + i * 16 + fq * 4 + q) * rld + blockIdx.x * WC + wc] = rp[i][q];
    }
    return;
  }

  #pragma unroll
  for (int i = 0; i < MR; i++) {
    const int mbase = tileM + wr * WSM + i * 16 + fq * 4;
    #pragma unroll
    for (int j = 0; j < NR; j++) {
      const int n = tileN + wc * WSN + j * 16 + fr;
      const float bv = bias ? bias[n] : 0.f;
      #pragma unroll
      for (int q = 0; q < 4; q++) {
        float v = acc[i][j][q] * alpha + bv;
        if constexpr (sizeof(CT) == 2)
          C[(long)(mbase + q) * N + coff + n] = f2bf(v);
        else
          C[(long)(mbase + q) * N + coff + n] = v;
      }
    }
  }
}

// ---- reduce 8 bf16 K-splits; in-block rowsum of rs_part -> rowinv; scale; cast bf16 ----
__global__ __launch_bounds__(256) void upd_reduce_k(const unsigned short* __restrict__ part,
                                                    const float* __restrict__ rs_part,
                                                    unsigned short* __restrict__ out) {
  const int row = blockIdx.x;  // b*64 + k
  const int tid = threadIdx.x;
  float s = (tid < 128) ? rs_part[(long)row * 128 + tid] : 0.f;
  #pragma unroll
  for (int off = 32; off; off >>= 1) s += __shfl_xor(s, off, 64);
  __shared__ float sb[4];
  if ((tid & 63) == 0) sb[tid >> 6] = s;
  __syncthreads();
  const float inv = 1.f / (sb[0] + sb[1] + sb[2] + sb[3] + 1e-6f);
  const unsigned short* base =
      part + (long)(row >> 6) * 8 * 65536 + (long)(row & 63) * 1024 + tid * 4;
  float ax = 0.f, ay = 0.f, az = 0.f, aw = 0.f;
  #pragma unroll
  for (int sp = 0; sp < 8; sp++) {
    ushort4 v = *(const ushort4*)(base + (long)sp * 65536);
    ax += bf2f(v.x); ay += bf2f(v.y); az += bf2f(v.z); aw += bf2f(v.w);
  }
  ushort4 o;
  o.x = f2bf(ax * inv); o.y = f2bf(ay * inv);
  o.z = f2bf(az * inv); o.w = f2bf(aw * inv);
  ((ushort4*)out)[(long)row * 256 + tid] = o;
}

// ---- GRU combine (bf16 gi / gh-in-qgh) + fused rmsnorm of the new slots ----
__global__ __launch_bounds__(256) void gru_k(const unsigned short* __restrict__ gi,
                                             const unsigned short* __restrict__ qgh,
                                             const float* __restrict__ h,
                                             const float* __restrict__ snw,
                                             float* __restrict__ out,
                                             unsigned short* __restrict__ out_bf,
                                             unsigned short* __restrict__ sn_out) {
  const int r = blockIdx.x;
  const int tid = threadIdx.x;
  const int c = tid * 4;
  const unsigned short* gip = gi + (long)r * 3072;
  const unsigned short* ghp = qgh + (long)r * 4096 + 1024;
  ushort4 iru = *(const ushort4*)(gip + c);
  ushort4 izu = *(const ushort4*)(gip + 1024 + c);
  ushort4 inu = *(const ushort4*)(gip + 2048 + c);
  ushort4 hru = *(const ushort4*)(ghp + c);
  ushort4 hzu = *(const ushort4*)(ghp + 1024 + c);
  ushort4 hnu = *(const ushort4*)(ghp + 2048 + c);
  float4 hv = *(const float4*)(h + (long)r * 1024 + c);
  float4 o;
  { float rr = sigm(bf2f(iru.x) + bf2f(hru.x)), zz = sigm(bf2f(izu.x) + bf2f(hzu.x));
    float nn = tanhf(bf2f(inu.x) + rr * bf2f(hnu.x)); o.x = (1.f - zz) * nn + zz * hv.x; }
  { float rr = sigm(bf2f(iru.y) + bf2f(hru.y)), zz = sigm(bf2f(izu.y) + bf2f(hzu.y));
    float nn = tanhf(bf2f(inu.y) + rr * bf2f(hnu.y)); o.y = (1.f - zz) * nn + zz * hv.y; }
  { float rr = sigm(bf2f(iru.z) + bf2f(hru.z)), zz = sigm(bf2f(izu.z) + bf2f(hzu.z));
    float nn = tanhf(bf2f(inu.z) + rr * bf2f(hnu.z)); o.z = (1.f - zz) * nn + zz * hv.z; }
  { float rr = sigm(bf2f(iru.w) + bf2f(hru.w)), zz = sigm(bf2f(izu.w) + bf2f(hzu.w));
    float nn = tanhf(bf2f(inu.w) + rr * bf2f(hnu.w)); o.w = (1.f - zz) * nn + zz * hv.w; }
  *(float4*)(out + (long)r * 1024 + c) = o;
  ushort4 ob;
  ob.x = f2bf(o.x); ob.y = f2bf(o.y); ob.z = f2bf(o.z); ob.w = f2bf(o.w);
  *(ushort4*)(out_bf + (long)r * 1024 + c) = ob;
  float ss = o.x * o.x + o.y * o.y + o.z * o.z + o.w * o.w;
  #pragma unroll
  for (int off = 32; off; off >>= 1) ss += __shfl_xor(ss, off, 64);
  __shared__ float sb[4];
  if ((tid & 63) == 0) sb[tid >> 6] = ss;
  __syncthreads();
  const float tot = sb[0] + sb[1] + sb[2] + sb[3];
  const float rs = rsqrtf(tot * (1.0f / 1024.0f) + 1e-6f);
  float4 wv = *(const float4*)(snw + c);
  ushort4 so;
  so.x = f2bf(o.x * rs * wv.x); so.y = f2bf(o.y * rs * wv.y);
  so.z = f2bf(o.z * rs * wv.z); so.w = f2bf(o.w * rs * wv.w);
  *(ushort4*)(sn_out + (long)r * 1024 + c) = so;
}

extern "C" void kernel_launch(void* const* d_in, const int* in_sizes, int n_in,
                              void* d_out, int out_size, void* d_ws, size_t ws_size,
                              hipStream_t stream) {
  const float* slots_in = (const float*)d_in[0];
  const float* P        = (const float*)d_in[1];
  const float* Wq       = (const float*)d_in[2];
  const float* Wk       = (const float*)d_in[3];
  const float* Wv       = (const float*)d_in[4];
  const float* wi       = (const float*)d_in[5];
  const float* wh       = (const float*)d_in[6];
  const float* bi       = (const float*)d_in[7];
  const float* bh       = (const float*)d_in[8];
  const float* snw      = (const float*)d_in[9];
  const float* inw      = (const float*)d_in[10];

  const size_t MB = 1024ull * 1024ull;
  char* ws = (char*)d_ws;
  unsigned short* Pn    = (unsigned short*)(ws + 0);        // 64MB [b][m][d] bf16 (persists)
  unsigned short* Pnt   = (unsigned short*)(ws + 64 * MB);  // 64MB [b][d][m] bf16 (persists)
  char* S               = ws + 128 * MB;                    // iteration region
  unsigned short* sn    = (unsigned short*)(S);             // 1MB
  unsigned short* qgh   = (unsigned short*)(S + 1 * MB);    // 4MB [512][4096]: qm | gh
  unsigned short* attnb = (unsigned short*)(S + 5 * MB);    // 4MB
  unsigned short* updb  = (unsigned short*)(S + 9 * MB);    // 1MB (t * rowinv, bf16)
  unsigned short* slotsb= (unsigned short*)(S + 10 * MB);   // 1MB
  unsigned short* gi_b  = (unsigned short*)(S + 11 * MB);   // 3MB [512][3072]
  unsigned short* Cpart = (unsigned short*)(S + 14 * MB);   // 8MB bf16 [64][64][1024]
  float* rs_part        = (float*)(S + 22 * MB);            // 256KB
  unsigned short* wi_b  = (unsigned short*)(S + 23 * MB);   // 6MB
  unsigned short* wh_b  = (unsigned short*)(S + 29 * MB);   // 6MB
  unsigned short* wqt   = (unsigned short*)(S + 35 * MB);   // 2MB (Wq^T bf16)
  unsigned short* wkt   = (unsigned short*)(S + 37 * MB);   // 2MB (Wk^T bf16)
  unsigned short* wvt   = (unsigned short*)(S + 39 * MB);   // 2MB (Wv^T bf16)
  unsigned short* m1_b  = (unsigned short*)(S + 41 * MB);   // 2MB  M1[m][n]=sum_e Wk[e,m]Wq[e,n]
  unsigned short* m2_b  = (unsigned short*)(S + 43 * MB);   // 6MB  M2[j][d]=sum_e wi[j,e]Wv[e,d]
  float* slots          = (float*)(ws + 196 * MB);          // 2MB

  // ---- prologue ----
  tcvt_k<<<dim3(16, 16, 3), 256, 0, stream>>>(Wq, Wk, Wv, wqt, wkt, wvt);
  rmsnorm_k<<<32768, 256, 0, stream>>>(P, inw, Pn, nullptr);
  tp_k<<<8192, 256, 0, stream>>>(Pn, Pnt);
  // M1 = Wk^T @ Wq
  gemm_bt<64, 64, 2, 2, unsigned short, 0, 1, 0>
      <<<dim3(16, 16, 1), 256, 0, stream>>>(wkt, wqt, m1_b, 1024, 1024, 1024, 1024,
                                            0, 0, 0, nullptr, nullptr, 1.f, nullptr,
                                            nullptr, nullptr);
  cvt2b_k<<<3072, 256, 0, stream>>>(wi, wh, wi_b, wh_b);
  // M2 = wi @ Wv  (C[j][d] = sum_e wi[j,e] Wv[e,d])
  gemm_bt<64, 64, 2, 2, unsigned short, 0, 1, 0>
      <<<dim3(16, 48, 1), 256, 0, stream>>>(wi_b, wvt, m2_b, 1024, 1024, 1024, 1024,
                                            0, 0, 0, nullptr, nullptr, 1.f, nullptr,
                                            nullptr, nullptr);
  // fused: sn = rmsnorm(slots_in), slotsb = bf16(slots_in)
  rmsnorm_k<<<512, 256, 0, stream>>>(slots_in, snw, sn, slotsb);

  // ---- 3 iterations (6 dispatches each) ----
  for (int it = 0; it < 3; ++it) {
    // merged qm+gh: z=0 -> qm = sn@M1^T into qgh[:, :1024]
    //               z=1..3 -> gh slab = slotsb@wh^T+bh into qgh[:, z*1024 ..)
    gemm_bt<64, 64, 2, 2, unsigned short, 0, 1, 1>
        <<<dim3(16, 8, 4), 256, 0, stream>>>(sn, m1_b, qgh, 4096, 1024, 1024, 1024,
                                             0, 0, 0, nullptr, bh, 1.f, nullptr,
                                             slotsb, wh_b);
    // attn[b][k][m] = softmax_k((qm_b @ Pn_b^T)/32) + row partials
    gemm_bt<64, 128, 1, 4, unsigned short, 2, 1, 0>
        <<<dim3(32, 1, 8), 256, 0, stream>>>(qgh, Pn, attnb, 4096, 1024, 4096, 1024,
                                             64L * 4096, 4096L * 1024, 64L * 4096,
                                             nullptr, nullptr, 0.03125f, rs_part,
                                             nullptr, nullptr);
    // t partials (bf16): attn_b @ Pnt_b^T, K=4096 split 8x512 (1024 blocks)
    gemm_bt<64, 64, 2, 2, unsigned short, 0, 8, 0>
        <<<dim3(16, 1, 64), 256, 0, stream>>>(attnb, Pnt, Cpart, 1024, 512, 4096, 4096,
                                              64L * 4096, 1024L * 4096, 64L * 1024,
                                              nullptr, nullptr, 1.f, nullptr,
                                              nullptr, nullptr);
    upd_reduce_k<<<512, 256, 0, stream>>>(Cpart, rs_part, updb);
    // gi = (t*rowinv) @ M2^T + bi -> bf16 [512][3072]
    gemm_bt<64, 64, 2, 2, unsigned short, 0, 1, 0>
        <<<dim3(48, 8, 1), 256, 0, stream>>>(updb, m2_b, gi_b, 3072, 1024, 1024, 1024,
                                             0, 0, 0, bi, nullptr, 1.f, nullptr,
                                             nullptr, nullptr);
    const float* hsrc = (it == 0) ? slots_in : slots;
    float* dst = (it == 2) ? (float*)d_out : slots;
    gru_k<<<512, 256, 0, stream>>>(gi_b, qgh, hsrc, snw, dst, slotsb, sn);
  }
}

// Round 14
// 348.674 us; speedup vs baseline: 1.2897x; 1.0215x over previous
//
#include <hip/hip_runtime.h>

typedef __attribute__((ext_vector_type(4))) float f32x4;
typedef __attribute__((ext_vector_type(8))) short s16x8;

static __device__ __forceinline__ unsigned short f2bf(float f) {
  unsigned int u = __builtin_bit_cast(unsigned int, f);
  u += 0x7fffu + ((u >> 16) & 1u);
  return (unsigned short)(u >> 16);
}
static __device__ __forceinline__ float bf2f(unsigned short u) {
  return __builtin_bit_cast(float, (unsigned int)u << 16);
}
static __device__ __forceinline__ float sigm(float x) { return 1.0f / (1.0f + __expf(-x)); }

// async global->LDS, 16B per lane. LDS dest = wave-uniform base + lane*16.
static __device__ __forceinline__ void gload16(const unsigned short* g, unsigned short* l) {
  __builtin_amdgcn_global_load_lds(
      (const __attribute__((address_space(1))) void*)g,
      (__attribute__((address_space(3))) void*)l, 16, 0, 0);
}

// ---------------- rmsnorm rows of length 1024: fp32 -> bf16 (+optional raw bf16) ----------------
__global__ __launch_bounds__(256) void rmsnorm_k(const float* __restrict__ x,
                                                 const float* __restrict__ w,
                                                 unsigned short* __restrict__ y,
                                                 unsigned short* __restrict__ y_raw) {
  const int row = blockIdx.x;
  const int tid = threadIdx.x;
  const float4* xp = (const float4*)(x + (long)row * 1024);
  float4 v = xp[tid];
  float ss = v.x * v.x + v.y * v.y + v.z * v.z + v.w * v.w;
  #pragma unroll
  for (int off = 32; off; off >>= 1) ss += __shfl_xor(ss, off, 64);
  __shared__ float sb[4];
  if ((tid & 63) == 0) sb[tid >> 6] = ss;
  __syncthreads();
  float tot = sb[0] + sb[1] + sb[2] + sb[3];
  float rs = rsqrtf(tot * (1.0f / 1024.0f) + 1e-6f);
  const float4* wp = (const float4*)w;
  float4 wv = wp[tid];
  ushort4 o;
  o.x = f2bf(v.x * rs * wv.x);
  o.y = f2bf(v.y * rs * wv.y);
  o.z = f2bf(v.z * rs * wv.z);
  o.w = f2bf(v.w * rs * wv.w);
  ((ushort4*)y)[(long)row * 256 + tid] = o;
  if (y_raw) {
    ushort4 r;
    r.x = f2bf(v.x); r.y = f2bf(v.y); r.z = f2bf(v.z); r.w = f2bf(v.w);
    ((ushort4*)y_raw)[(long)row * 256 + tid] = r;
  }
}

// ---------------- bf16 transpose: Pn[b][4096 m][1024 d] -> Pnt[b][1024 d][4096 m] ----------------
__global__ __launch_bounds__(256) void tp_k(const unsigned short* __restrict__ in,
                                            unsigned short* __restrict__ out) {
  __shared__ unsigned short t[64][65];
  const int x = blockIdx.x;
  const int b = x >> 10;
  const int mt = (x & 1023) >> 4;
  const int dt = x & 15;
  const int tid = threadIdx.x;
  const long ibase = (long)b * 4096 * 1024 + (long)mt * 64 * 1024 + dt * 64;
  #pragma unroll
  for (int i = 0; i < 4; i++) {
    int idx = tid + i * 256;
    int r = idx >> 4, c4 = (idx & 15) * 4;
    ushort4 v = *(const ushort4*)(in + ibase + (long)r * 1024 + c4);
    t[r][c4] = v.x; t[r][c4 + 1] = v.y; t[r][c4 + 2] = v.z; t[r][c4 + 3] = v.w;
  }
  __syncthreads();
  const long obase = (long)b * 1024 * 4096 + (long)dt * 64 * 4096 + mt * 64;
  #pragma unroll
  for (int i = 0; i < 4; i++) {
    int idx = tid + i * 256;
    int r = idx >> 4, c4 = (idx & 15) * 4;
    ushort4 o;
    o.x = t[c4][r]; o.y = t[c4 + 1][r]; o.z = t[c4 + 2][r]; o.w = t[c4 + 3][r];
    *(ushort4*)(out + obase + (long)r * 4096 + c4) = o;
  }
}

// ---------------- fp32->bf16 convert chunk ----------------
static __device__ __forceinline__ void cvt_chunk(const float* __restrict__ in,
                                                 unsigned short* __restrict__ out, long i) {
  const float4* p = (const float4*)in;
  float4 a = p[i * 2], b = p[i * 2 + 1];
  ushort4 lo, hi;
  lo.x = f2bf(a.x); lo.y = f2bf(a.y); lo.z = f2bf(a.z); lo.w = f2bf(a.w);
  hi.x = f2bf(b.x); hi.y = f2bf(b.y); hi.z = f2bf(b.z); hi.w = f2bf(b.w);
  ushort4* o = (ushort4*)out;
  o[i * 2] = lo;
  o[i * 2 + 1] = hi;
}

// ---------------- combined prologue prep ----------------
// grid 4352: [0,768)    transpose-cvt Wq/Wk/Wv -> wqt/wkt/wvt (64x64 tiles)
//            [768,3840) cvt wi (1536 blocks) then wh (1536 blocks)
//            [3840,4352) rmsnorm(slots_in) -> sn + raw bf16 -> slotsb
__global__ __launch_bounds__(256) void prep_k(
    const float* __restrict__ Wq, const float* __restrict__ Wk, const float* __restrict__ Wv,
    const float* __restrict__ wi, const float* __restrict__ wh,
    const float* __restrict__ slots_in, const float* __restrict__ snw,
    unsigned short* __restrict__ wqt, unsigned short* __restrict__ wkt,
    unsigned short* __restrict__ wvt, unsigned short* __restrict__ wi_b,
    unsigned short* __restrict__ wh_b, unsigned short* __restrict__ sn,
    unsigned short* __restrict__ slotsb) {
  __shared__ float tile[64][65];
  const int x = blockIdx.x;
  const int tid = threadIdx.x;
  if (x < 768) {
    const int z = x >> 8, t = x & 255;
    const float* in = (z == 0) ? Wq : (z == 1) ? Wk : Wv;
    unsigned short* out = (z == 0) ? wqt : (z == 1) ? wkt : wvt;
    const int r0 = (t >> 4) * 64, c0 = (t & 15) * 64;
    #pragma unroll
    for (int i = 0; i < 4; i++) {
      int idx = tid + i * 256;
      int r = idx >> 4, c4 = (idx & 15) * 4;
      float4 v = *(const float4*)(in + (long)(r0 + r) * 1024 + c0 + c4);
      tile[r][c4] = v.x; tile[r][c4 + 1] = v.y; tile[r][c4 + 2] = v.z; tile[r][c4 + 3] = v.w;
    }
    __syncthreads();
    #pragma unroll
    for (int i = 0; i < 4; i++) {
      int idx = tid + i * 256;
      int c = idx >> 4, r4 = (idx & 15) * 4;
      ushort4 o;
      o.x = f2bf(tile[r4][c]);     o.y = f2bf(tile[r4 + 1][c]);
      o.z = f2bf(tile[r4 + 2][c]); o.w = f2bf(tile[r4 + 3][c]);
      *(ushort4*)(out + (long)(c0 + c) * 1024 + r0 + r4) = o;
    }
  } else if (x < 3840) {
    const int y = x - 768;
    if (y < 1536) cvt_chunk(wi, wi_b, (long)y * 256 + tid);
    else          cvt_chunk(wh, wh_b, (long)(y - 1536) * 256 + tid);
  } else {
    const int row = x - 3840;
    const float4* xp = (const float4*)(slots_in + (long)row * 1024);
    float4 v = xp[tid];
    float ss = v.x * v.x + v.y * v.y + v.z * v.z + v.w * v.w;
    #pragma unroll
    for (int off = 32; off; off >>= 1) ss += __shfl_xor(ss, off, 64);
    float* sb = &tile[0][0];
    if ((tid & 63) == 0) sb[tid >> 6] = ss;
    __syncthreads();
    float tot = sb[0] + sb[1] + sb[2] + sb[3];
    float rs = rsqrtf(tot * (1.0f / 1024.0f) + 1e-6f);
    float4 wv = ((const float4*)snw)[tid];
    ushort4 o;
    o.x = f2bf(v.x * rs * wv.x); o.y = f2bf(v.y * rs * wv.y);
    o.z = f2bf(v.z * rs * wv.z); o.w = f2bf(v.w * rs * wv.w);
    ((ushort4*)sn)[(long)row * 256 + tid] = o;
    ushort4 r;
    r.x = f2bf(v.x); r.y = f2bf(v.y); r.z = f2bf(v.z); r.w = f2bf(v.w);
    ((ushort4*)slotsb)[(long)row * 256 + tid] = r;
  }
}

// ---------------- GEMM: C = alpha * A[M][K] @ W[N][K]^T (+bias) ----------------
// EPI: 0 = plain store; 2 = softmax over M(=64) -> bf16 attn + row partials.
// SPLIT: K-split batching. QGH: z=0 -> A/W cols[0,1024); z>0 -> A2/W2 slab.
template <int BM, int BN, int WR, int WC, typename CT, int EPI, int SPLIT, int QGH>
__global__ __launch_bounds__(WR * WC * 64) void gemm_bt(
    const unsigned short* __restrict__ A, const unsigned short* __restrict__ W,
    CT* __restrict__ C, int N, int Klen, int lda, int ldw,
    long sA, long sW, long sC, const float* __restrict__ bias,
    const float* __restrict__ bias2, float alpha, float* __restrict__ rs_part,
    const unsigned short* __restrict__ A2, const unsigned short* __restrict__ W2) {
  constexpr int BK = 64;
  constexpr int NT = WR * WC * 64;
  static_assert(NT == 256, "256 threads");
  constexpr int WSM = BM / WR, WSN = BN / WC;
  constexpr int MR = WSM / 16, NR = WSN / 16;
  constexpr int SEG_A = BM / 8, SEG_W = BN / 8;
  constexpr int PA = SEG_A / 4, PW = SEG_W / 4;
  static_assert(SEG_A % 4 == 0 && SEG_W % 4 == 0, "seg divisibility");
  __shared__ unsigned short As[BM * BK];
  __shared__ unsigned short Ws[BN * BK];
  const int tid = threadIdx.x, lane = tid & 63, wid = tid >> 6;
  const int wr = wid / WC, wc = wid % WC;
  const int tileN = blockIdx.x * BN, tileM = blockIdx.y * BM;
  int coff = 0;
  int zb = 0;
  if constexpr (QGH) {
    const int zz = blockIdx.z;
    if (zz > 0) {
      A = A2;
      W = W2 + (long)(zz - 1) * 1024 * ldw;
      bias = bias2 + (zz - 1) * 1024;
      coff = zz * 1024;
    }
  } else {
    zb = blockIdx.z / SPLIT;
    const int zs = blockIdx.z % SPLIT;
    A += (long)zb * sA + (long)zs * Klen;
    W += (long)zb * sW + (long)zs * Klen;
    C += (long)blockIdx.z * sC;
  }
  const int srow = lane >> 3;
  const int scol = (lane & 7) * 8;
  f32x4 acc[MR][NR];
  #pragma unroll
  for (int i = 0; i < MR; i++)
    #pragma unroll
    for (int j = 0; j < NR; j++) acc[i][j] = (f32x4){0.f, 0.f, 0.f, 0.f};
  const int fr = lane & 15, fq = lane >> 4;

  for (int k0 = 0; k0 < Klen; k0 += BK) {
    #pragma unroll
    for (int p = 0; p < PA; p++) {
      int seg = wid * PA + p;
      gload16(A + (long)(tileM + seg * 8 + srow) * lda + k0 + scol, &As[seg * 512]);
    }
    #pragma unroll
    for (int p = 0; p < PW; p++) {
      int seg = wid * PW + p;
      gload16(W + (long)(tileN + seg * 8 + srow) * ldw + k0 + scol, &Ws[seg * 512]);
    }
    __syncthreads();
    #pragma unroll
    for (int kk = 0; kk < BK; kk += 32) {
      s16x8 af[MR], bf[NR];
      #pragma unroll
      for (int i = 0; i < MR; i++)
        af[i] = *(const s16x8*)(&As[(wr * WSM + i * 16 + fr) * BK + kk + fq * 8]);
      #pragma unroll
      for (int j = 0; j < NR; j++)
        bf[j] = *(const s16x8*)(&Ws[(wc * WSN + j * 16 + fr) * BK + kk + fq * 8]);
      #pragma unroll
      for (int i = 0; i < MR; i++)
        #pragma unroll
        for (int j = 0; j < NR; j++)
          acc[i][j] = __builtin_amdgcn_mfma_f32_16x16x32_bf16(af[i], bf[j], acc[i][j], 0, 0, 0);
    }
    __syncthreads();
  }

  if constexpr (EPI == 2) {
    static_assert(WR == 1 && BM == 64, "softmax epilogue needs full-M wave");
    #pragma unroll
    for (int i = 0; i < MR; i++)
      #pragma unroll
      for (int j = 0; j < NR; j++)
        #pragma unroll
        for (int q = 0; q < 4; q++) acc[i][j][q] *= alpha;
    float inv[NR];
    #pragma unroll
    for (int j = 0; j < NR; j++) {
      float mx = -1e30f;
      #pragma unroll
      for (int i = 0; i < MR; i++)
        #pragma unroll
        for (int q = 0; q < 4; q++) mx = fmaxf(mx, acc[i][j][q]);
      mx = fmaxf(mx, __shfl_xor(mx, 16, 64));
      mx = fmaxf(mx, __shfl_xor(mx, 32, 64));
      float sm = 0.f;
      #pragma unroll
      for (int i = 0; i < MR; i++)
        #pragma unroll
        for (int q = 0; q < 4; q++) {
          float e = __expf(acc[i][j][q] - mx);
          acc[i][j][q] = e;
          sm += e;
        }
      sm += __shfl_xor(sm, 16, 64);
      sm += __shfl_xor(sm, 32, 64);
      inv[j] = 1.f / sm;
    }
    float rp[MR][4];
    #pragma unroll
    for (int i = 0; i < MR; i++)
      #pragma unroll
      for (int q = 0; q < 4; q++) rp[i][q] = 0.f;
    unsigned short* Cs = (unsigned short*)C;
    #pragma unroll
    for (int i = 0; i < MR; i++)
      #pragma unroll
      for (int j = 0; j < NR; j++)
        #pragma unroll
        for (int q = 0; q < 4; q++) {
          float a = acc[i][j][q] * inv[j];
          rp[i][q] += a;
          Cs[(long)(i * 16 + fq * 4 + q) * N + tileN + wc * WSN + j * 16 + fr] = f2bf(a);
        }
    #pragma unroll
    for (int off = 1; off <= 8; off <<= 1)
      #pragma unroll
      for (int i = 0; i < MR; i++)
        #pragma unroll
        for (int q = 0; q < 4; q++) rp[i][q] += __shfl_xor(rp[i][q], off, 64);
    if (fr == 0) {
      const int rld = gridDim.x * WC;
      #pragma unroll
      for (int i = 0; i < MR; i++)
        #pragma unroll
        for (int q = 0; q < 4; q++)
          rs_part[((long)zb * 64 + i * 16 + fq * 4 + q) * rld + blockIdx.x * WC + wc] = rp[i][q];
    }
    return;
  }

  #pragma unroll
  for (int i = 0; i < MR; i++) {
    const int mbase = tileM + wr * WSM + i * 16 + fq * 4;
    #pragma unroll
    for (int j = 0; j < NR; j++) {
      const int n = tileN + wc * WSN + j * 16 + fr;
      const float bv = bias ? bias[n] : 0.f;
      #pragma unroll
      for (int q = 0; q < 4; q++) {
        float v = acc[i][j][q] * alpha + bv;
        if constexpr (sizeof(CT) == 2)
          C[(long)(mbase + q) * N + coff + n] = f2bf(v);
        else
          C[(long)(mbase + q) * N + coff + n] = v;
      }
    }
  }
}

// ---- reduce 8 bf16 K-splits; in-block rowsum of rs_part (256 partials) -> rowinv; scale; bf16 ----
__global__ __launch_bounds__(256) void upd_reduce_k(const unsigned short* __restrict__ part,
                                                    const float* __restrict__ rs_part,
                                                    unsigned short* __restrict__ out) {
  const int row = blockIdx.x;  // b*64 + k
  const int tid = threadIdx.x;
  float s = rs_part[(long)row * 256 + tid];
  #pragma unroll
  for (int off = 32; off; off >>= 1) s += __shfl_xor(s, off, 64);
  __shared__ float sb[4];
  if ((tid & 63) == 0) sb[tid >> 6] = s;
  __syncthreads();
  const float inv = 1.f / (sb[0] + sb[1] + sb[2] + sb[3] + 1e-6f);
  const unsigned short* base =
      part + (long)(row >> 6) * 8 * 65536 + (long)(row & 63) * 1024 + tid * 4;
  float ax = 0.f, ay = 0.f, az = 0.f, aw = 0.f;
  #pragma unroll
  for (int sp = 0; sp < 8; sp++) {
    ushort4 v = *(const ushort4*)(base + (long)sp * 65536);
    ax += bf2f(v.x); ay += bf2f(v.y); az += bf2f(v.z); aw += bf2f(v.w);
  }
  ushort4 o;
  o.x = f2bf(ax * inv); o.y = f2bf(ay * inv);
  o.z = f2bf(az * inv); o.w = f2bf(aw * inv);
  ((ushort4*)out)[(long)row * 256 + tid] = o;
}

// ---- GRU combine (bf16 gi / gh-in-qgh) + fused rmsnorm of the new slots ----
__global__ __launch_bounds__(256) void gru_k(const unsigned short* __restrict__ gi,
                                             const unsigned short* __restrict__ qgh,
                                             const float* __restrict__ h,
                                             const float* __restrict__ snw,
                                             float* __restrict__ out,
                                             unsigned short* __restrict__ out_bf,
                                             unsigned short* __restrict__ sn_out) {
  const int r = blockIdx.x;
  const int tid = threadIdx.x;
  const int c = tid * 4;
  const unsigned short* gip = gi + (long)r * 3072;
  const unsigned short* ghp = qgh + (long)r * 4096 + 1024;
  ushort4 iru = *(const ushort4*)(gip + c);
  ushort4 izu = *(const ushort4*)(gip + 1024 + c);
  ushort4 inu = *(const ushort4*)(gip + 2048 + c);
  ushort4 hru = *(const ushort4*)(ghp + c);
  ushort4 hzu = *(const ushort4*)(ghp + 1024 + c);
  ushort4 hnu = *(const ushort4*)(ghp + 2048 + c);
  float4 hv = *(const float4*)(h + (long)r * 1024 + c);
  float4 o;
  { float rr = sigm(bf2f(iru.x) + bf2f(hru.x)), zz = sigm(bf2f(izu.x) + bf2f(hzu.x));
    float nn = tanhf(bf2f(inu.x) + rr * bf2f(hnu.x)); o.x = (1.f - zz) * nn + zz * hv.x; }
  { float rr = sigm(bf2f(iru.y) + bf2f(hru.y)), zz = sigm(bf2f(izu.y) + bf2f(hzu.y));
    float nn = tanhf(bf2f(inu.y) + rr * bf2f(hnu.y)); o.y = (1.f - zz) * nn + zz * hv.y; }
  { float rr = sigm(bf2f(iru.z) + bf2f(hru.z)), zz = sigm(bf2f(izu.z) + bf2f(hzu.z));
    float nn = tanhf(bf2f(inu.z) + rr * bf2f(hnu.z)); o.z = (1.f - zz) * nn + zz * hv.z; }
  { float rr = sigm(bf2f(iru.w) + bf2f(hru.w)), zz = sigm(bf2f(izu.w) + bf2f(hzu.w));
    float nn = tanhf(bf2f(inu.w) + rr * bf2f(hnu.w)); o.w = (1.f - zz) * nn + zz * hv.w; }
  *(float4*)(out + (long)r * 1024 + c) = o;
  ushort4 ob;
  ob.x = f2bf(o.x); ob.y = f2bf(o.y); ob.z = f2bf(o.z); ob.w = f2bf(o.w);
  *(ushort4*)(out_bf + (long)r * 1024 + c) = ob;
  float ss = o.x * o.x + o.y * o.y + o.z * o.z + o.w * o.w;
  #pragma unroll
  for (int off = 32; off; off >>= 1) ss += __shfl_xor(ss, off, 64);
  __shared__ float sb[4];
  if ((tid & 63) == 0) sb[tid >> 6] = ss;
  __syncthreads();
  const float tot = sb[0] + sb[1] + sb[2] + sb[3];
  const float rs = rsqrtf(tot * (1.0f / 1024.0f) + 1e-6f);
  float4 wv = *(const float4*)(snw + c);
  ushort4 so;
  so.x = f2bf(o.x * rs * wv.x); so.y = f2bf(o.y * rs * wv.y);
  so.z = f2bf(o.z * rs * wv.z); so.w = f2bf(o.w * rs * wv.w);
  *(ushort4*)(sn_out + (long)r * 1024 + c) = so;
}

extern "C" void kernel_launch(void* const* d_in, const int* in_sizes, int n_in,
                              void* d_out, int out_size, void* d_ws, size_t ws_size,
                              hipStream_t stream) {
  const float* slots_in = (const float*)d_in[0];
  const float* P        = (const float*)d_in[1];
  const float* Wq       = (const float*)d_in[2];
  const float* Wk       = (const float*)d_in[3];
  const float* Wv       = (const float*)d_in[4];
  const float* wi       = (const float*)d_in[5];
  const float* wh       = (const float*)d_in[6];
  const float* bi       = (const float*)d_in[7];
  const float* bh       = (const float*)d_in[8];
  const float* snw      = (const float*)d_in[9];
  const float* inw      = (const float*)d_in[10];

  const size_t MB = 1024ull * 1024ull;
  char* ws = (char*)d_ws;
  unsigned short* Pn    = (unsigned short*)(ws + 0);        // 64MB [b][m][d] bf16 (persists)
  unsigned short* Pnt   = (unsigned short*)(ws + 64 * MB);  // 64MB [b][d][m] bf16 (persists)
  char* S               = ws + 128 * MB;                    // iteration region
  unsigned short* sn    = (unsigned short*)(S);             // 1MB
  unsigned short* qgh   = (unsigned short*)(S + 1 * MB);    // 4MB [512][4096]: qm | gh
  unsigned short* attnb = (unsigned short*)(S + 5 * MB);    // 4MB
  unsigned short* updb  = (unsigned short*)(S + 9 * MB);    // 1MB (t * rowinv, bf16)
  unsigned short* slotsb= (unsigned short*)(S + 10 * MB);   // 1MB
  unsigned short* gi_b  = (unsigned short*)(S + 11 * MB);   // 3MB [512][3072]
  unsigned short* Cpart = (unsigned short*)(S + 14 * MB);   // 8MB bf16 [64][64][1024]
  float* rs_part        = (float*)(S + 22 * MB);            // 512KB [512][256]
  unsigned short* wi_b  = (unsigned short*)(S + 23 * MB);   // 6MB
  unsigned short* wh_b  = (unsigned short*)(S + 29 * MB);   // 6MB
  unsigned short* wqt   = (unsigned short*)(S + 35 * MB);   // 2MB (Wq^T bf16)
  unsigned short* wkt   = (unsigned short*)(S + 37 * MB);   // 2MB (Wk^T bf16)
  unsigned short* wvt   = (unsigned short*)(S + 39 * MB);   // 2MB (Wv^T bf16)
  unsigned short* m1_b  = (unsigned short*)(S + 41 * MB);   // 2MB  M1[m][n]=sum_e Wk[e,m]Wq[e,n]
  unsigned short* m2_b  = (unsigned short*)(S + 43 * MB);   // 6MB  M2[j][d]=sum_e wi[j,e]Wv[e,d]
  float* slots          = (float*)(ws + 196 * MB);          // 2MB

  // ---- prologue (5 dispatches) ----
  prep_k<<<4352, 256, 0, stream>>>(Wq, Wk, Wv, wi, wh, slots_in, snw,
                                   wqt, wkt, wvt, wi_b, wh_b, sn, slotsb);
  rmsnorm_k<<<32768, 256, 0, stream>>>(P, inw, Pn, nullptr);
  tp_k<<<8192, 256, 0, stream>>>(Pn, Pnt);
  // M1 = Wk^T @ Wq
  gemm_bt<64, 64, 2, 2, unsigned short, 0, 1, 0>
      <<<dim3(16, 16, 1), 256, 0, stream>>>(wkt, wqt, m1_b, 1024, 1024, 1024, 1024,
                                            0, 0, 0, nullptr, nullptr, 1.f, nullptr,
                                            nullptr, nullptr);
  // M2 = wi @ Wv
  gemm_bt<64, 64, 2, 2, unsigned short, 0, 1, 0>
      <<<dim3(16, 48, 1), 256, 0, stream>>>(wi_b, wvt, m2_b, 1024, 1024, 1024, 1024,
                                            0, 0, 0, nullptr, nullptr, 1.f, nullptr,
                                            nullptr, nullptr);

  // ---- 3 iterations (6 dispatches each) ----
  for (int it = 0; it < 3; ++it) {
    // merged qm+gh: z=0 -> qm = sn@M1^T; z=1..3 -> gh slab = slotsb@wh^T+bh
    gemm_bt<64, 64, 2, 2, unsigned short, 0, 1, 1>
        <<<dim3(16, 8, 4), 256, 0, stream>>>(sn, m1_b, qgh, 4096, 1024, 1024, 1024,
                                             0, 0, 0, nullptr, bh, 1.f, nullptr,
                                             slotsb, wh_b);
    // attn[b][k][m] = softmax_k((qm_b @ Pn_b^T)/32) + row partials (BN=64, 512 blocks)
    gemm_bt<64, 64, 1, 4, unsigned short, 2, 1, 0>
        <<<dim3(64, 1, 8), 256, 0, stream>>>(qgh, Pn, attnb, 4096, 1024, 4096, 1024,
                                             64L * 4096, 4096L * 1024, 64L * 4096,
                                             nullptr, nullptr, 0.03125f, rs_part,
                                             nullptr, nullptr);
    // t partials (bf16): attn_b @ Pnt_b^T, K=4096 split 8x512 (1024 blocks)
    gemm_bt<64, 64, 2, 2, unsigned short, 0, 8, 0>
        <<<dim3(16, 1, 64), 256, 0, stream>>>(attnb, Pnt, Cpart, 1024, 512, 4096, 4096,
                                              64L * 4096, 1024L * 4096, 64L * 1024,
                                              nullptr, nullptr, 1.f, nullptr,
                                              nullptr, nullptr);
    upd_reduce_k<<<512, 256, 0, stream>>>(Cpart, rs_part, updb);
    // gi = (t*rowinv) @ M2^T + bi -> bf16 [512][3072]
    gemm_bt<64, 64, 2, 2, unsigned short, 0, 1, 0>
        <<<dim3(48, 8, 1), 256, 0, stream>>>(updb, m2_b, gi_b, 3072, 1024, 1024, 1024,
                                             0, 0, 0, bi, nullptr, 1.f, nullptr,
                                             nullptr, nullptr);
    const float* hsrc = (it == 0) ? slots_in : slots;
    float* dst = (it == 2) ? (float*)d_out : slots;
    gru_k<<<512, 256, 0, stream>>>(gi_b, qgh, hsrc, snw, dst, slotsb, sn);
  }
}